// Round 10
// baseline (758.555 us; speedup 1.0000x reference)
//
#include <hip/hip_runtime.h>
#include <hip/hip_fp16.h>

#define NF 14
#define DIMOUT 16
#define BSH 9        // 512 nodes per bucket
#define NPBKT 512
#define NBKT 256     // bucket count (used: ceil(N/512) = 196)
#define C1 4096      // edges per block in bucket passes

// int64 edge buffer <=> odd 32-bit words (high halves) all zero (ids < 2^31)
__device__ __forceinline__ bool detect64(const int* e32) {
    bool is64 = true;
#pragma unroll
    for (int i = 1; i < 64; i += 2) is64 &= (e32[i] == 0);
    return is64;
}

// ---- per-block bucket histogram (transposed write) ----
__global__ __launch_bounds__(256) void k_lhist(const void* __restrict__ edges,
                                               int* __restrict__ lhistT, int E, int NBLK) {
    __shared__ int h[NBKT];
    const int t = threadIdx.x;
    h[t] = 0;
    __syncthreads();
    const int* e32 = (const int*)edges;
    const long long* e64 = (const long long*)edges;
    const bool is64 = detect64(e32);
    const int base = blockIdx.x * C1;
    const int cnt = min(C1, E - base);
    for (int j = t; j < cnt; j += 256) {
        int i = base + j;
        int dst = is64 ? (int)__builtin_nontemporal_load(e64 + (size_t)E + i)
                       : __builtin_nontemporal_load(e32 + (size_t)E + i);
        atomicAdd(&h[dst >> BSH], 1);
    }
    __syncthreads();
    lhistT[(size_t)t * NBLK + blockIdx.x] = h[t];
}

// ---- per-bucket scan over blocks ----
__global__ __launch_bounds__(256) void k_cscan(const int* __restrict__ lhistT,
                                               int* __restrict__ lbase,
                                               int* __restrict__ btot, int NBLK) {
    const int b = blockIdx.x;
    const int t = threadIdx.x;
    const int IPT = (NBLK + 255) / 256;
    int v[8];
    int s = 0;
    for (int k = 0; k < IPT; ++k) {
        int j = t * IPT + k;
        int x = (j < NBLK) ? lhistT[(size_t)b * NBLK + j] : 0;
        v[k] = x;
        s += x;
    }
    __shared__ int sm[256];
    sm[t] = s;
    __syncthreads();
    for (int d = 1; d < 256; d <<= 1) {
        int u = (t >= d) ? sm[t - d] : 0;
        __syncthreads();
        sm[t] += u;
        __syncthreads();
    }
    int run = sm[t] - s;
    for (int k = 0; k < IPT; ++k) {
        int j = t * IPT + k;
        if (j < NBLK) {
            lbase[(size_t)b * NBLK + j] = run;
            run += v[k];
        }
    }
    if (t == 255) btot[b] = sm[255];
}

// ---- scan bucket totals -> regions ----
__global__ __launch_bounds__(NBKT) void k_gscan(const int* __restrict__ btot,
                                                int* __restrict__ gregion) {
    __shared__ int sm[NBKT];
    int t = threadIdx.x;
    int v = btot[t];
    sm[t] = v;
    __syncthreads();
    for (int d = 1; d < NBKT; d <<= 1) {
        int u = (t >= d) ? sm[t - d] : 0;
        __syncthreads();
        sm[t] += u;
        __syncthreads();
    }
    gregion[t] = sm[t] - v;
    if (t == NBKT - 1) gregion[NBKT] = sm[t];
}

// ---- bucket scatter: block-local LDS counting sort, runs at exact bases ----
// packed entry: (dst & 511) << 17 | src
__global__ __launch_bounds__(256) void k_scatter(const void* __restrict__ edges,
                                                 const int* __restrict__ gregion,
                                                 const int* __restrict__ lbase,
                                                 unsigned int* __restrict__ pairs,
                                                 int E, int NBLK) {
    __shared__ unsigned int raw[C1];
    __shared__ unsigned int srt[C1];
    __shared__ unsigned short bkt[C1];
    __shared__ unsigned char sbk[C1];
    __shared__ int hist[NBKT], scn[NBKT], gb[NBKT], cur[NBKT];
    const int* e32 = (const int*)edges;
    const long long* e64 = (const long long*)edges;
    const bool is64 = detect64(e32);
    const int t = threadIdx.x;
    const int base = blockIdx.x * C1;
    const int cnt = min(C1, E - base);
    hist[t] = 0;
    cur[t] = 0;
    __syncthreads();
    for (int j = t; j < cnt; j += 256) {
        int i = base + j;
        int src, dst;
        if (is64) {
            src = (int)__builtin_nontemporal_load(e64 + i);
            dst = (int)__builtin_nontemporal_load(e64 + (size_t)E + i);
        } else {
            src = __builtin_nontemporal_load(e32 + i);
            dst = __builtin_nontemporal_load(e32 + (size_t)E + i);
        }
        int b = dst >> BSH;
        raw[j] = (unsigned int)src | ((unsigned int)(dst & (NPBKT - 1)) << 17);
        bkt[j] = (unsigned short)b;
        atomicAdd(&hist[b], 1);
    }
    __syncthreads();
    int v = hist[t];
    scn[t] = v;
    __syncthreads();
    for (int d = 1; d < NBKT; d <<= 1) {
        int u = (t >= d) ? scn[t - d] : 0;
        __syncthreads();
        scn[t] += u;
        __syncthreads();
    }
    int ex = scn[t] - v;
    gb[t] = gregion[t] + lbase[(size_t)t * NBLK + blockIdx.x];
    __syncthreads();
    scn[t] = ex;
    __syncthreads();
    for (int j = t; j < cnt; j += 256) {
        int b = bkt[j];
        int r = atomicAdd(&cur[b], 1);
        int pos = scn[b] + r;
        srt[pos] = raw[j];
        sbk[pos] = (unsigned char)b;
    }
    __syncthreads();
    for (int j = t; j < cnt; j += 256) {
        int b = sbk[j];
        pairs[gb[b] + (j - scn[b])] = srt[j];
    }
}

// ---- prep: per-bucket degree histogram -> dinv; u0 = fp16(dinv * (x @ W^T)) ----
__global__ __launch_bounds__(256) void k_prep(const unsigned int* __restrict__ pairs,
                                              const int* __restrict__ gregion,
                                              const float* __restrict__ x,
                                              const float* __restrict__ Wg,
                                              float* __restrict__ dinv,
                                              __half2* __restrict__ u0, int N) {
    const int b = blockIdx.x, t = threadIdx.x;
    const int e0 = gregion[b], e1 = gregion[b + 1];
    __shared__ int deg[NPBKT];
    __shared__ float Wl[DIMOUT * NF];
    if (t < DIMOUT * NF) Wl[t] = Wg[t];
    deg[t] = 0;
    deg[t + 256] = 0;
    __syncthreads();
    for (int e = e0 + t; e < e1; e += 256) atomicAdd(&deg[pairs[e] >> 17], 1);
    __syncthreads();
    const int nbase = b << BSH;
#pragma unroll
    for (int rep = 0; rep < 2; ++rep) {
        const int l = t + rep * 256;
        const int n = nbase + l;
        if (n < N) {
            float dn = rsqrtf((float)(deg[l] + 1));
            dinv[n] = dn;
            float xr[NF];
            const float2* xr2 = (const float2*)(x + (size_t)n * NF);
#pragma unroll
            for (int k = 0; k < 7; ++k) {
                float2 v = xr2[k];
                xr[2 * k] = v.x;
                xr[2 * k + 1] = v.y;
            }
#pragma unroll
            for (int q = 0; q < 8; ++q) {
                float r0 = 0.f, r1 = 0.f;
#pragma unroll
                for (int f = 0; f < NF; ++f) {
                    r0 += xr[f] * Wl[(2 * q) * NF + f];
                    r1 += xr[f] * Wl[(2 * q + 1) * NF + f];
                }
                u0[(size_t)n * 8 + q] = __floats2half2_rn(dn * r0, dn * r1);
            }
        }
    }
}

// ---- fused hop: one 1024-thread block per 512-node bucket.
// Stream pairs (coalesced), gather u[src] (8 lanes/edge, fp16 rows in L2),
// accumulate via LDS fp32 atomics (fire-and-forget -> deep pipelining).
// FINAL=0: u1 = fp16(dn^2 * (acc + self))   FINAL=1: out = dn*(acc+self)+bias
template <int FINAL>
__global__ __launch_bounds__(1024) void k_hop(const __half2* __restrict__ u,
                                              const unsigned int* __restrict__ pairs,
                                              const int* __restrict__ gregion,
                                              const float* __restrict__ dinv,
                                              const float* __restrict__ bias,
                                              __half2* __restrict__ outh,
                                              float* __restrict__ outf, int N) {
    const int b = blockIdx.x, t = threadIdx.x;
    const int e0 = gregion[b], e1 = gregion[b + 1];
    __shared__ float acc[NPBKT][16];  // 32 KB
    for (int i = t; i < NPBKT * 16; i += 1024) ((float*)acc)[i] = 0.f;
    __syncthreads();
    const int f = t & 7;   // half2 lane within row
    const int g = t >> 3;  // 0..127 edge groups
#pragma unroll 2
    for (int e = e0 + g; e < e1; e += 128) {
        unsigned p = pairs[e];
        int src = p & 0x1FFFF;
        int dl = p >> 17;
        float2 v = __half22float2(u[(size_t)src * 8 + f]);
        atomicAdd(&acc[dl][2 * f], v.x);
        atomicAdd(&acc[dl][2 * f + 1], v.y);
    }
    __syncthreads();
    // finalize: 2 threads per node, 8 floats each
    const int l = t >> 1;
    const int n = (b << BSH) + l;
    if (n >= N) return;
    const int q0 = (t & 1) * 4;  // half2 base: 0 or 4
    float dn = dinv[n];
    float2 s0 = __half22float2(u[(size_t)n * 8 + q0]);
    float2 s1 = __half22float2(u[(size_t)n * 8 + q0 + 1]);
    float2 s2 = __half22float2(u[(size_t)n * 8 + q0 + 2]);
    float2 s3 = __half22float2(u[(size_t)n * 8 + q0 + 3]);
    float a0 = acc[l][2 * q0] + s0.x, a1 = acc[l][2 * q0 + 1] + s0.y;
    float a2 = acc[l][2 * q0 + 2] + s1.x, a3 = acc[l][2 * q0 + 3] + s1.y;
    float a4 = acc[l][2 * q0 + 4] + s2.x, a5 = acc[l][2 * q0 + 5] + s2.y;
    float a6 = acc[l][2 * q0 + 6] + s3.x, a7 = acc[l][2 * q0 + 7] + s3.y;
    if (!FINAL) {
        float sc = dn * dn;
        outh[(size_t)n * 8 + q0] = __floats2half2_rn(sc * a0, sc * a1);
        outh[(size_t)n * 8 + q0 + 1] = __floats2half2_rn(sc * a2, sc * a3);
        outh[(size_t)n * 8 + q0 + 2] = __floats2half2_rn(sc * a4, sc * a5);
        outh[(size_t)n * 8 + q0 + 3] = __floats2half2_rn(sc * a6, sc * a7);
    } else {
        float4 o0, o1;
        o0.x = dn * a0 + bias[2 * q0];
        o0.y = dn * a1 + bias[2 * q0 + 1];
        o0.z = dn * a2 + bias[2 * q0 + 2];
        o0.w = dn * a3 + bias[2 * q0 + 3];
        o1.x = dn * a4 + bias[2 * q0 + 4];
        o1.y = dn * a5 + bias[2 * q0 + 5];
        o1.z = dn * a6 + bias[2 * q0 + 6];
        o1.w = dn * a7 + bias[2 * q0 + 7];
        *(float4*)(outf + (size_t)n * DIMOUT + 2 * q0) = o0;
        *(float4*)(outf + (size_t)n * DIMOUT + 2 * q0 + 4) = o1;
    }
}

extern "C" void kernel_launch(void* const* d_in, const int* in_sizes, int n_in,
                              void* d_out, int out_size, void* d_ws, size_t ws_size,
                              hipStream_t stream) {
    const float* x = (const float*)d_in[0];
    const void* edges = d_in[1];
    const float* W = (const float*)d_in[2];
    const float* b = (const float*)d_in[3];
    float* out = (float*)d_out;

    const int N = in_sizes[0] / NF;  // 100000
    const int E = in_sizes[1] / 2;   // 3200000
    const int NBLK = (E + C1 - 1) / C1;
    const int NUSED = (N + NPBKT - 1) >> BSH;

    char* ws = (char*)d_ws;
    size_t o = 0;
    auto alloc = [&](size_t bytes) -> void* {
        o = (o + 255) & ~(size_t)255;
        void* p = ws + o;
        o += bytes;
        return p;
    };
    int* lhistT = (int*)alloc((size_t)NBKT * NBLK * sizeof(int));
    int* lbase = (int*)alloc((size_t)NBKT * NBLK * sizeof(int));
    int* btot = (int*)alloc((size_t)NBKT * sizeof(int));
    int* gregion = (int*)alloc(((size_t)NBKT + 1) * sizeof(int));
    unsigned int* pairs = (unsigned int*)alloc((size_t)E * sizeof(unsigned int));
    float* dinv = (float*)alloc((size_t)N * sizeof(float));
    __half* u0 = (__half*)alloc((size_t)N * 16 * sizeof(__half));
    __half* u1 = (__half*)alloc((size_t)N * 16 * sizeof(__half));
    (void)ws_size;
    (void)n_in;
    (void)out_size;

    k_lhist<<<NBLK, 256, 0, stream>>>(edges, lhistT, E, NBLK);
    k_cscan<<<NBKT, 256, 0, stream>>>(lhistT, lbase, btot, NBLK);
    k_gscan<<<1, NBKT, 0, stream>>>(btot, gregion);
    k_scatter<<<NBLK, 256, 0, stream>>>(edges, gregion, lbase, pairs, E, NBLK);
    k_prep<<<NUSED, 256, 0, stream>>>(pairs, gregion, x, W, dinv, (__half2*)u0, N);

    k_hop<0><<<NUSED, 1024, 0, stream>>>((const __half2*)u0, pairs, gregion, dinv,
                                         nullptr, (__half2*)u1, nullptr, N);
    k_hop<1><<<NUSED, 1024, 0, stream>>>((const __half2*)u1, pairs, gregion, dinv,
                                         b, nullptr, out, N);
}

// Round 11
// 190.469 us; speedup vs baseline: 3.9826x; 3.9826x over previous
//
#include <hip/hip_runtime.h>
#include <hip/hip_fp16.h>

#define NF 14
#define DIMOUT 16
#define BSH 9        // 512 nodes per bucket
#define NPBKT 512
#define NBKT 256     // bucket count (used: ceil(N/512) = 196)
#define C1 4096      // edges per block in bucket passes
#define GSUB 8       // subchunks per bucket in node-level passes

// int64 edge buffer <=> odd 32-bit words (high halves) all zero (ids < 2^31)
__device__ __forceinline__ bool detect64(const int* e32) {
    bool is64 = true;
#pragma unroll
    for (int i = 1; i < 64; i += 2) is64 &= (e32[i] == 0);
    return is64;
}

// ---- per-block bucket histogram (transposed write) ----
__global__ __launch_bounds__(256) void k_lhist(const void* __restrict__ edges,
                                               int* __restrict__ lhistT, int E, int NBLK) {
    __shared__ int h[NBKT];
    const int t = threadIdx.x;
    h[t] = 0;
    __syncthreads();
    const int* e32 = (const int*)edges;
    const long long* e64 = (const long long*)edges;
    const bool is64 = detect64(e32);
    const int base = blockIdx.x * C1;
    const int cnt = min(C1, E - base);
    for (int j = t; j < cnt; j += 256) {
        int i = base + j;
        int dst = is64 ? (int)e64[(size_t)E + i] : e32[(size_t)E + i];
        atomicAdd(&h[dst >> BSH], 1);
    }
    __syncthreads();
    lhistT[(size_t)t * NBLK + blockIdx.x] = h[t];
}

// ---- per-bucket scan over blocks ----
__global__ __launch_bounds__(256) void k_cscan(const int* __restrict__ lhistT,
                                               int* __restrict__ lbase,
                                               int* __restrict__ btot, int NBLK) {
    const int b = blockIdx.x;
    const int t = threadIdx.x;
    const int IPT = (NBLK + 255) / 256;
    int v[8];
    int s = 0;
    for (int k = 0; k < IPT; ++k) {
        int j = t * IPT + k;
        int x = (j < NBLK) ? lhistT[(size_t)b * NBLK + j] : 0;
        v[k] = x;
        s += x;
    }
    __shared__ int sm[256];
    sm[t] = s;
    __syncthreads();
    for (int d = 1; d < 256; d <<= 1) {
        int u = (t >= d) ? sm[t - d] : 0;
        __syncthreads();
        sm[t] += u;
        __syncthreads();
    }
    int run = sm[t] - s;
    for (int k = 0; k < IPT; ++k) {
        int j = t * IPT + k;
        if (j < NBLK) {
            lbase[(size_t)b * NBLK + j] = run;
            run += v[k];
        }
    }
    if (t == 255) btot[b] = sm[255];
}

// ---- scan bucket totals -> regions ----
__global__ __launch_bounds__(NBKT) void k_gscan(const int* __restrict__ btot,
                                                int* __restrict__ gregion) {
    __shared__ int sm[NBKT];
    int t = threadIdx.x;
    int v = btot[t];
    sm[t] = v;
    __syncthreads();
    for (int d = 1; d < NBKT; d <<= 1) {
        int u = (t >= d) ? sm[t - d] : 0;
        __syncthreads();
        sm[t] += u;
        __syncthreads();
    }
    gregion[t] = sm[t] - v;
    if (t == NBKT - 1) gregion[NBKT] = sm[t];
}

// ---- bucket scatter: block-local LDS counting sort, runs at exact bases ----
// packed entry: (dst & 511) << 17 | src
__global__ __launch_bounds__(256) void k_scatter(const void* __restrict__ edges,
                                                 const int* __restrict__ gregion,
                                                 const int* __restrict__ lbase,
                                                 unsigned int* __restrict__ pairs,
                                                 int E, int NBLK) {
    __shared__ unsigned int raw[C1];
    __shared__ unsigned int srt[C1];
    __shared__ unsigned short bkt[C1];
    __shared__ unsigned char sbk[C1];
    __shared__ int hist[NBKT], scn[NBKT], gb[NBKT], cur[NBKT];
    const int* e32 = (const int*)edges;
    const long long* e64 = (const long long*)edges;
    const bool is64 = detect64(e32);
    const int t = threadIdx.x;
    const int base = blockIdx.x * C1;
    const int cnt = min(C1, E - base);
    hist[t] = 0;
    cur[t] = 0;
    __syncthreads();
    for (int j = t; j < cnt; j += 256) {
        int i = base + j;
        int src, dst;
        if (is64) {
            src = (int)e64[i];
            dst = (int)e64[(size_t)E + i];
        } else {
            src = e32[i];
            dst = e32[(size_t)E + i];
        }
        int b = dst >> BSH;
        raw[j] = (unsigned int)src | ((unsigned int)(dst & (NPBKT - 1)) << 17);
        bkt[j] = (unsigned short)b;
        atomicAdd(&hist[b], 1);
    }
    __syncthreads();
    int v = hist[t];
    scn[t] = v;
    __syncthreads();
    for (int d = 1; d < NBKT; d <<= 1) {
        int u = (t >= d) ? scn[t - d] : 0;
        __syncthreads();
        scn[t] += u;
        __syncthreads();
    }
    int ex = scn[t] - v;
    gb[t] = gregion[t] + lbase[(size_t)t * NBLK + blockIdx.x];
    __syncthreads();
    scn[t] = ex;
    __syncthreads();
    for (int j = t; j < cnt; j += 256) {
        int b = bkt[j];
        int r = atomicAdd(&cur[b], 1);
        int pos = scn[b] + r;
        srt[pos] = raw[j];
        sbk[pos] = (unsigned char)b;
    }
    __syncthreads();
    for (int j = t; j < cnt; j += 256) {
        int b = sbk[j];
        pairs[gb[b] + (j - scn[b])] = srt[j];
    }
}

// ---- node-level histogram per (bucket, subchunk); g-major layout ----
__global__ __launch_bounds__(256) void k_nhist(const unsigned int* __restrict__ pairs,
                                               const int* __restrict__ gregion,
                                               int* __restrict__ nh, int N) {
    const int b = blockIdx.x >> 3;
    const int g = blockIdx.x & 7;
    const int e0 = gregion[b], e1 = gregion[b + 1];
    const int L = e1 - e0;
    const int sb = e0 + ((L * g) >> 3);
    const int se = e0 + ((L * (g + 1)) >> 3);
    __shared__ int h[NPBKT];
    const int t = threadIdx.x;
    h[t] = 0;
    h[t + 256] = 0;
    __syncthreads();
    for (int e = sb + t; e < se; e += 256) atomicAdd(&h[pairs[e] >> 17], 1);
    __syncthreads();
    const int nbase = b << BSH;
    for (int l = t; l < NPBKT; l += 256) {
        int n = nbase + l;
        if (n < N) nh[(size_t)g * N + n] = h[l];
    }
}

// ---- per-node scan over subchunks + block scan of padded degrees ----
// padded slots = round_up(deg + 1, 32): self-loop in-list, pad to 32
__global__ __launch_bounds__(256) void k_nscan(int* __restrict__ nh,
                                               float* __restrict__ dinv,
                                               int2* __restrict__ lc,
                                               int* __restrict__ btot2, int N) {
    const int t = threadIdx.x;
    const int n = blockIdx.x * 256 + t;
    int c = 0, p = 0;
    if (n < N) {
        int v[GSUB];
        int ex = 0;
#pragma unroll
        for (int g = 0; g < GSUB; ++g) v[g] = nh[(size_t)g * N + n];
#pragma unroll
        for (int g = 0; g < GSUB; ++g) {
            int vv = v[g];
            nh[(size_t)g * N + n] = ex;  // counts -> exclusive bases (in place)
            ex += vv;
        }
        c = ex;
        p = (c + 32) & ~31;  // self-loop + pad to multiple of 32
        dinv[n] = rsqrtf((float)(c + 1));
    }
    __shared__ int sm[256];
    sm[t] = p;
    __syncthreads();
    for (int d = 1; d < 256; d <<= 1) {
        int u = (t >= d) ? sm[t - d] : 0;
        __syncthreads();
        sm[t] += u;
        __syncthreads();
    }
    if (n < N) lc[n] = make_int2(sm[t] - p, c);  // (local offset, degree)
    if (t == 255) btot2[blockIdx.x] = sm[255];
}

// ---- scan per-block padded totals ----
__global__ __launch_bounds__(512) void k_gscan2(const int* __restrict__ btot2,
                                                int* __restrict__ bbase2, int nb) {
    __shared__ int sm[512];
    int t = threadIdx.x;
    int v = (t < nb) ? btot2[t] : 0;
    sm[t] = v;
    __syncthreads();
    for (int d = 1; d < 512; d <<= 1) {
        int u = (t >= d) ? sm[t - d] : 0;
        __syncthreads();
        sm[t] += u;
        __syncthreads();
    }
    if (t < nb) bbase2[t] = sm[t] - v;
}

// ---- finalize offsets, self-loop entries, sentinel pads ----
__global__ __launch_bounds__(256) void k_nfill(const int2* __restrict__ lc,
                                               const int* __restrict__ bbase2,
                                               int2* __restrict__ off2,
                                               int* __restrict__ srcs, int N) {
    const int n = blockIdx.x * 256 + threadIdx.x;
    if (n >= N) return;
    int2 l = lc[n];
    const int off = bbase2[blockIdx.x] + l.x;
    const int c = l.y;
    const int p = (c + 32) & ~31;
    off2[n] = make_int2(off, off + p);
    srcs[off] = n;  // self loop at slot 0
    for (int k = c + 1; k < p; ++k) srcs[off + k] = N;  // sentinel pad
}

// ---- node-level scatter per (bucket, subchunk) at precomputed bases ----
__global__ __launch_bounds__(256) void k_nscatter(const unsigned int* __restrict__ pairs,
                                                  const int* __restrict__ gregion,
                                                  const int* __restrict__ nh,
                                                  const int2* __restrict__ off2,
                                                  int* __restrict__ srcs, int N) {
    const int b = blockIdx.x >> 3;
    const int g = blockIdx.x & 7;
    const int e0 = gregion[b], e1 = gregion[b + 1];
    const int L = e1 - e0;
    const int sb = e0 + ((L * g) >> 3);
    const int se = e0 + ((L * (g + 1)) >> 3);
    __shared__ int cur[NPBKT];
    const int t = threadIdx.x;
    const int nbase = b << BSH;
    for (int l = t; l < NPBKT; l += 256) {
        int n = nbase + l;
        if (n < N) cur[l] = off2[n].x + 1 + nh[(size_t)g * N + n];
    }
    __syncthreads();
    for (int e = sb + t; e < se; e += 256) {
        unsigned int pr = pairs[e];
        int l = pr >> 17;
        int r = atomicAdd(&cur[l], 1);  // LDS only
        srcs[r] = (int)(pr & 0x1FFFFu);
    }
}

// ---- prep: u0[n] = fp16( dinv[n] * (x[n] @ W^T) ); zero sentinel rows ----
__global__ __launch_bounds__(256) void k_prep(const float* __restrict__ x,
                                              const float* __restrict__ dinv,
                                              const float* __restrict__ Wg,
                                              __half2* __restrict__ u0,
                                              __half2* __restrict__ u1, int N) {
    __shared__ float Wl[DIMOUT * NF];
    int t = threadIdx.x;
    if (t < DIMOUT * NF) Wl[t] = Wg[t];
    __syncthreads();
    if (blockIdx.x == 0 && t < 8) {  // zero sentinel rows (src == N)
        u0[(size_t)N * 8 + t] = __floats2half2_rn(0.f, 0.f);
        u1[(size_t)N * 8 + t] = __floats2half2_rn(0.f, 0.f);
    }
    int n = blockIdx.x * 256 + t;
    if (n >= N) return;
    float xr[NF];
    const float2* xr2 = (const float2*)(x + (size_t)n * NF);
#pragma unroll
    for (int k = 0; k < 7; ++k) {
        float2 v = xr2[k];
        xr[2 * k] = v.x;
        xr[2 * k + 1] = v.y;
    }
    float dn = dinv[n];
#pragma unroll
    for (int q = 0; q < 8; ++q) {
        float r0 = 0.f, r1 = 0.f;
#pragma unroll
        for (int f = 0; f < NF; ++f) {
            r0 += xr[f] * Wl[(2 * q) * NF + f];
            r1 += xr[f] * Wl[(2 * q + 1) * NF + f];
        }
        u0[(size_t)n * 8 + q] = __floats2half2_rn(dn * r0, dn * r1);
    }
}

// ---- hop: wave per node, 32-way edge-parallel, 16B lanes, padded lists ----
// lane = ep*2 + fp: fp = which 16B half of the 32B fp16 row, ep = edge subgroup
// FINAL=0: u1 = fp16(dn^2 * acc)   FINAL=1: out = dn * acc + bias (fp32)
template <int FINAL>
__global__ __launch_bounds__(256) void k_hop(const uint4* __restrict__ u16,
                                             const int* __restrict__ srcs,
                                             const int2* __restrict__ off2,
                                             const float* __restrict__ dinv,
                                             const float* __restrict__ bias,
                                             uint4* __restrict__ outh,
                                             float* __restrict__ outf, int N) {
    const int lane = threadIdx.x & 63;
    const int fp = lane & 1;   // 16B half of row (features 8*fp .. 8*fp+7)
    const int ep = lane >> 1;  // 0..31 edge-parallel subgroup
    const int n = blockIdx.x * 4 + (threadIdx.x >> 6);
    if (n >= N) return;  // wave-uniform
    const int2 oo = off2[n];
    const int beg = oo.x, end = oo.y;  // (end-beg) % 32 == 0, >= 32
    float a0 = 0.f, a1 = 0.f, a2 = 0.f, a3 = 0.f;
    float a4 = 0.f, a5 = 0.f, a6 = 0.f, a7 = 0.f;
    auto accq = [&](uint4 q) {
        float2 v0 = __half22float2(*(__half2*)&q.x);
        float2 v1 = __half22float2(*(__half2*)&q.y);
        float2 v2 = __half22float2(*(__half2*)&q.z);
        float2 v3 = __half22float2(*(__half2*)&q.w);
        a0 += v0.x;
        a1 += v0.y;
        a2 += v1.x;
        a3 += v1.y;
        a4 += v2.x;
        a5 += v2.y;
        a6 += v3.x;
        a7 += v3.y;
    };
    int e = beg + ep;
    for (; e + 32 < end; e += 64) {  // 2-deep: 64 edges per wave-iteration
        int s0 = srcs[e];
        int s1 = srcs[e + 32];
        uint4 q0 = u16[(size_t)s0 * 2 + fp];
        uint4 q1 = u16[(size_t)s1 * 2 + fp];
        accq(q0);
        accq(q1);
    }
    if (e < end) {  // one leftover 32-chunk, fully lane-parallel
        int s0 = srcs[e];
        uint4 q0 = u16[(size_t)s0 * 2 + fp];
        accq(q0);
    }
#pragma unroll
    for (int d = 2; d <= 32; d <<= 1) {
        a0 += __shfl_xor(a0, d);
        a1 += __shfl_xor(a1, d);
        a2 += __shfl_xor(a2, d);
        a3 += __shfl_xor(a3, d);
        a4 += __shfl_xor(a4, d);
        a5 += __shfl_xor(a5, d);
        a6 += __shfl_xor(a6, d);
        a7 += __shfl_xor(a7, d);
    }
    if (ep != 0) return;  // lanes 0,1 hold full sums for their 16B half
    float dn = dinv[n];
    if (!FINAL) {
        float sc = dn * dn;
        __half2 h0 = __floats2half2_rn(sc * a0, sc * a1);
        __half2 h1 = __floats2half2_rn(sc * a2, sc * a3);
        __half2 h2 = __floats2half2_rn(sc * a4, sc * a5);
        __half2 h3 = __floats2half2_rn(sc * a6, sc * a7);
        uint4 q;
        q.x = *(unsigned*)&h0;
        q.y = *(unsigned*)&h1;
        q.z = *(unsigned*)&h2;
        q.w = *(unsigned*)&h3;
        outh[(size_t)n * 2 + fp] = q;
    } else {
        const float* bp = bias + 8 * fp;
        float4 o0, o1;
        o0.x = dn * a0 + bp[0];
        o0.y = dn * a1 + bp[1];
        o0.z = dn * a2 + bp[2];
        o0.w = dn * a3 + bp[3];
        o1.x = dn * a4 + bp[4];
        o1.y = dn * a5 + bp[5];
        o1.z = dn * a6 + bp[6];
        o1.w = dn * a7 + bp[7];
        float* op = outf + (size_t)n * DIMOUT + 8 * fp;
        *(float4*)op = o0;
        *(float4*)(op + 4) = o1;
    }
}

extern "C" void kernel_launch(void* const* d_in, const int* in_sizes, int n_in,
                              void* d_out, int out_size, void* d_ws, size_t ws_size,
                              hipStream_t stream) {
    const float* x = (const float*)d_in[0];
    const void* edges = d_in[1];
    const float* W = (const float*)d_in[2];
    const float* b = (const float*)d_in[3];
    float* out = (float*)d_out;

    const int N = in_sizes[0] / NF;  // 100000
    const int E = in_sizes[1] / 2;   // 3200000
    const int NBLK = (E + C1 - 1) / C1;
    const int NUSED = (N + NPBKT - 1) >> BSH;
    const int NBLK2 = (N + 255) / 256;

    char* ws = (char*)d_ws;
    size_t o = 0;
    auto alloc = [&](size_t bytes) -> void* {
        o = (o + 255) & ~(size_t)255;
        void* p = ws + o;
        o += bytes;
        return p;
    };
    int* lhistT = (int*)alloc((size_t)NBKT * NBLK * sizeof(int));
    int* lbase = (int*)alloc((size_t)NBKT * NBLK * sizeof(int));
    int* btot = (int*)alloc((size_t)NBKT * sizeof(int));
    int* gregion = (int*)alloc(((size_t)NBKT + 1) * sizeof(int));
    unsigned int* pairs = (unsigned int*)alloc((size_t)E * sizeof(unsigned int));
    int* srcs = (int*)alloc(((size_t)E + (size_t)33 * N + 256) * sizeof(int));
    int* nh = (int*)alloc((size_t)GSUB * N * sizeof(int));
    int2* lc = (int2*)alloc((size_t)N * sizeof(int2));
    int* btot2 = (int*)alloc((size_t)NBLK2 * sizeof(int));
    int* bbase2 = (int*)alloc((size_t)NBLK2 * sizeof(int));
    int2* off2 = (int2*)alloc((size_t)N * sizeof(int2));
    float* dinv = (float*)alloc((size_t)N * sizeof(float));
    __half* u0 = (__half*)alloc((size_t)(N + 1) * 16 * sizeof(__half));
    __half* u1 = (__half*)alloc((size_t)(N + 1) * 16 * sizeof(__half));
    (void)ws_size;
    (void)n_in;
    (void)out_size;

    k_lhist<<<NBLK, 256, 0, stream>>>(edges, lhistT, E, NBLK);
    k_cscan<<<NBKT, 256, 0, stream>>>(lhistT, lbase, btot, NBLK);
    k_gscan<<<1, NBKT, 0, stream>>>(btot, gregion);
    k_scatter<<<NBLK, 256, 0, stream>>>(edges, gregion, lbase, pairs, E, NBLK);
    k_nhist<<<NUSED * GSUB, 256, 0, stream>>>(pairs, gregion, nh, N);
    k_nscan<<<NBLK2, 256, 0, stream>>>(nh, dinv, lc, btot2, N);
    k_prep<<<NBLK2, 256, 0, stream>>>(x, dinv, W, (__half2*)u0, (__half2*)u1, N);
    k_gscan2<<<1, 512, 0, stream>>>(btot2, bbase2, NBLK2);
    k_nfill<<<NBLK2, 256, 0, stream>>>(lc, bbase2, off2, srcs, N);
    k_nscatter<<<NUSED * GSUB, 256, 0, stream>>>(pairs, gregion, nh, off2, srcs, N);

    int hopgrid = (N + 3) / 4;
    k_hop<0><<<hopgrid, 256, 0, stream>>>((const uint4*)u0, srcs, off2, dinv, nullptr,
                                          (uint4*)u1, nullptr, N);
    k_hop<1><<<hopgrid, 256, 0, stream>>>((const uint4*)u1, srcs, off2, dinv, b,
                                          nullptr, out, N);
}

// Round 12
// 186.279 us; speedup vs baseline: 4.0721x; 1.0225x over previous
//
#include <hip/hip_runtime.h>
#include <hip/hip_fp16.h>

#define NF 14
#define DIMOUT 16
#define BSH 9        // 512 nodes per bucket
#define NPBKT 512
#define NBKT 256     // bucket count (used: ceil(N/512) = 196)
#define C1 4096      // edges per block in bucket passes
#define GSUB 8       // subchunks per bucket in node-level passes

// int64 edge buffer <=> odd 32-bit words (high halves) all zero (ids < 2^31)
__device__ __forceinline__ bool detect64(const int* e32) {
    bool is64 = true;
#pragma unroll
    for (int i = 1; i < 64; i += 2) is64 &= (e32[i] == 0);
    return is64;
}

// ---- per-block bucket histogram (transposed write) ----
__global__ __launch_bounds__(256) void k_lhist(const void* __restrict__ edges,
                                               int* __restrict__ lhistT, int E, int NBLK) {
    __shared__ int h[NBKT];
    const int t = threadIdx.x;
    h[t] = 0;
    __syncthreads();
    const int* e32 = (const int*)edges;
    const long long* e64 = (const long long*)edges;
    const bool is64 = detect64(e32);
    const int base = blockIdx.x * C1;
    const int cnt = min(C1, E - base);
    for (int j = t; j < cnt; j += 256) {
        int i = base + j;
        int dst = is64 ? (int)__builtin_nontemporal_load(e64 + (size_t)E + i)
                       : __builtin_nontemporal_load(e32 + (size_t)E + i);
        atomicAdd(&h[dst >> BSH], 1);
    }
    __syncthreads();
    lhistT[(size_t)t * NBLK + blockIdx.x] = h[t];
}

// ---- per-bucket scan over blocks ----
__global__ __launch_bounds__(256) void k_cscan(const int* __restrict__ lhistT,
                                               int* __restrict__ lbase,
                                               int* __restrict__ btot, int NBLK) {
    const int b = blockIdx.x;
    const int t = threadIdx.x;
    const int IPT = (NBLK + 255) / 256;
    int v[8];
    int s = 0;
    for (int k = 0; k < IPT; ++k) {
        int j = t * IPT + k;
        int x = (j < NBLK) ? lhistT[(size_t)b * NBLK + j] : 0;
        v[k] = x;
        s += x;
    }
    __shared__ int sm[256];
    sm[t] = s;
    __syncthreads();
    for (int d = 1; d < 256; d <<= 1) {
        int u = (t >= d) ? sm[t - d] : 0;
        __syncthreads();
        sm[t] += u;
        __syncthreads();
    }
    int run = sm[t] - s;
    for (int k = 0; k < IPT; ++k) {
        int j = t * IPT + k;
        if (j < NBLK) {
            lbase[(size_t)b * NBLK + j] = run;
            run += v[k];
        }
    }
    if (t == 255) btot[b] = sm[255];
}

// ---- scan bucket totals -> regions ----
__global__ __launch_bounds__(NBKT) void k_gscan(const int* __restrict__ btot,
                                                int* __restrict__ gregion) {
    __shared__ int sm[NBKT];
    int t = threadIdx.x;
    int v = btot[t];
    sm[t] = v;
    __syncthreads();
    for (int d = 1; d < NBKT; d <<= 1) {
        int u = (t >= d) ? sm[t - d] : 0;
        __syncthreads();
        sm[t] += u;
        __syncthreads();
    }
    gregion[t] = sm[t] - v;
    if (t == NBKT - 1) gregion[NBKT] = sm[t];
}

// ---- bucket scatter: block-local LDS counting sort, runs at exact bases ----
// packed entry: (dst & 511) << 17 | src
__global__ __launch_bounds__(256) void k_scatter(const void* __restrict__ edges,
                                                 const int* __restrict__ gregion,
                                                 const int* __restrict__ lbase,
                                                 unsigned int* __restrict__ pairs,
                                                 int E, int NBLK) {
    __shared__ unsigned int raw[C1];
    __shared__ unsigned int srt[C1];
    __shared__ unsigned short bkt[C1];
    __shared__ unsigned char sbk[C1];
    __shared__ int hist[NBKT], scn[NBKT], gb[NBKT], cur[NBKT];
    const int* e32 = (const int*)edges;
    const long long* e64 = (const long long*)edges;
    const bool is64 = detect64(e32);
    const int t = threadIdx.x;
    const int base = blockIdx.x * C1;
    const int cnt = min(C1, E - base);
    hist[t] = 0;
    cur[t] = 0;
    __syncthreads();
    for (int j = t; j < cnt; j += 256) {
        int i = base + j;
        int src, dst;
        if (is64) {
            src = (int)__builtin_nontemporal_load(e64 + i);
            dst = (int)__builtin_nontemporal_load(e64 + (size_t)E + i);
        } else {
            src = __builtin_nontemporal_load(e32 + i);
            dst = __builtin_nontemporal_load(e32 + (size_t)E + i);
        }
        int b = dst >> BSH;
        raw[j] = (unsigned int)src | ((unsigned int)(dst & (NPBKT - 1)) << 17);
        bkt[j] = (unsigned short)b;
        atomicAdd(&hist[b], 1);
    }
    __syncthreads();
    int v = hist[t];
    scn[t] = v;
    __syncthreads();
    for (int d = 1; d < NBKT; d <<= 1) {
        int u = (t >= d) ? scn[t - d] : 0;
        __syncthreads();
        scn[t] += u;
        __syncthreads();
    }
    int ex = scn[t] - v;
    gb[t] = gregion[t] + lbase[(size_t)t * NBLK + blockIdx.x];
    __syncthreads();
    scn[t] = ex;
    __syncthreads();
    for (int j = t; j < cnt; j += 256) {
        int b = bkt[j];
        int r = atomicAdd(&cur[b], 1);
        int pos = scn[b] + r;
        srt[pos] = raw[j];
        sbk[pos] = (unsigned char)b;
    }
    __syncthreads();
    for (int j = t; j < cnt; j += 256) {
        int b = sbk[j];
        pairs[gb[b] + (j - scn[b])] = srt[j];
    }
}

// ---- node-level histogram per (bucket, subchunk); g-major layout ----
__global__ __launch_bounds__(256) void k_nhist(const unsigned int* __restrict__ pairs,
                                               const int* __restrict__ gregion,
                                               int* __restrict__ nh, int N) {
    const int b = blockIdx.x >> 3;
    const int g = blockIdx.x & 7;
    const int e0 = gregion[b], e1 = gregion[b + 1];
    const int L = e1 - e0;
    const int sb = e0 + ((L * g) >> 3);
    const int se = e0 + ((L * (g + 1)) >> 3);
    __shared__ int h[NPBKT];
    const int t = threadIdx.x;
    h[t] = 0;
    h[t + 256] = 0;
    __syncthreads();
    for (int e = sb + t; e < se; e += 256) atomicAdd(&h[pairs[e] >> 17], 1);
    __syncthreads();
    const int nbase = b << BSH;
    for (int l = t; l < NPBKT; l += 256) {
        int n = nbase + l;
        if (n < N) nh[(size_t)g * N + n] = h[l];
    }
}

// ---- per-node scan over subchunks + block scan of padded degrees
//      + FUSED prep: u0[n] = fp16(dinv * (x[n] @ W^T)), sentinel-row zeroing ----
__global__ __launch_bounds__(256) void k_nscan(int* __restrict__ nh,
                                               float* __restrict__ dinv,
                                               int2* __restrict__ lc,
                                               int* __restrict__ btot2,
                                               const float* __restrict__ x,
                                               const float* __restrict__ Wg,
                                               __half2* __restrict__ u0,
                                               __half2* __restrict__ u1, int N) {
    __shared__ float Wl[DIMOUT * NF];
    __shared__ int sm[256];
    const int t = threadIdx.x;
    if (t < DIMOUT * NF) Wl[t] = Wg[t];
    if (blockIdx.x == 0 && t < 8) {  // zero sentinel rows (src == N)
        u0[(size_t)N * 8 + t] = __floats2half2_rn(0.f, 0.f);
        u1[(size_t)N * 8 + t] = __floats2half2_rn(0.f, 0.f);
    }
    const int n = blockIdx.x * 256 + t;
    int c = 0, p = 0;
    float dn = 0.f;
    if (n < N) {
        int v[GSUB];
        int ex = 0;
#pragma unroll
        for (int g = 0; g < GSUB; ++g) v[g] = nh[(size_t)g * N + n];
#pragma unroll
        for (int g = 0; g < GSUB; ++g) {
            int vv = v[g];
            nh[(size_t)g * N + n] = ex;  // counts -> exclusive bases (in place)
            ex += vv;
        }
        c = ex;
        p = (c + 16) & ~15;  // self-loop + pad to multiple of 16
        dn = rsqrtf((float)(c + 1));
        dinv[n] = dn;
    }
    sm[t] = p;
    __syncthreads();
    for (int d = 1; d < 256; d <<= 1) {
        int u = (t >= d) ? sm[t - d] : 0;
        __syncthreads();
        sm[t] += u;
        __syncthreads();
    }
    if (n < N) {
        lc[n] = make_int2(sm[t] - p, c);  // (local offset, degree)
        float xr[NF];
        const float2* xr2 = (const float2*)(x + (size_t)n * NF);
#pragma unroll
        for (int k = 0; k < 7; ++k) {
            float2 v2 = xr2[k];
            xr[2 * k] = v2.x;
            xr[2 * k + 1] = v2.y;
        }
#pragma unroll
        for (int q = 0; q < 8; ++q) {
            float r0 = 0.f, r1 = 0.f;
#pragma unroll
            for (int f = 0; f < NF; ++f) {
                r0 += xr[f] * Wl[(2 * q) * NF + f];
                r1 += xr[f] * Wl[(2 * q + 1) * NF + f];
            }
            u0[(size_t)n * 8 + q] = __floats2half2_rn(dn * r0, dn * r1);
        }
    }
    if (t == 255) btot2[blockIdx.x] = sm[255];
}

// ---- scan per-block padded totals ----
__global__ __launch_bounds__(512) void k_gscan2(const int* __restrict__ btot2,
                                                int* __restrict__ bbase2, int nb) {
    __shared__ int sm[512];
    int t = threadIdx.x;
    int v = (t < nb) ? btot2[t] : 0;
    sm[t] = v;
    __syncthreads();
    for (int d = 1; d < 512; d <<= 1) {
        int u = (t >= d) ? sm[t - d] : 0;
        __syncthreads();
        sm[t] += u;
        __syncthreads();
    }
    if (t < nb) bbase2[t] = sm[t] - v;
}

// ---- finalize offsets, self-loop entries, sentinel pads ----
__global__ __launch_bounds__(256) void k_nfill(const int2* __restrict__ lc,
                                               const int* __restrict__ bbase2,
                                               int2* __restrict__ off2,
                                               int* __restrict__ srcs, int N) {
    const int n = blockIdx.x * 256 + threadIdx.x;
    if (n >= N) return;
    int2 l = lc[n];
    const int off = bbase2[blockIdx.x] + l.x;
    const int c = l.y;
    const int p = (c + 16) & ~15;
    off2[n] = make_int2(off, off + p);
    srcs[off] = n;  // self loop at slot 0
    for (int k = c + 1; k < p; ++k) srcs[off + k] = N;  // sentinel pad
}

// ---- node-level scatter per (bucket, subchunk) at precomputed bases ----
__global__ __launch_bounds__(256) void k_nscatter(const unsigned int* __restrict__ pairs,
                                                  const int* __restrict__ gregion,
                                                  const int* __restrict__ nh,
                                                  const int2* __restrict__ off2,
                                                  int* __restrict__ srcs, int N) {
    const int b = blockIdx.x >> 3;
    const int g = blockIdx.x & 7;
    const int e0 = gregion[b], e1 = gregion[b + 1];
    const int L = e1 - e0;
    const int sb = e0 + ((L * g) >> 3);
    const int se = e0 + ((L * (g + 1)) >> 3);
    __shared__ int cur[NPBKT];
    const int t = threadIdx.x;
    const int nbase = b << BSH;
    for (int l = t; l < NPBKT; l += 256) {
        int n = nbase + l;
        if (n < N) cur[l] = off2[n].x + 1 + nh[(size_t)g * N + n];
    }
    __syncthreads();
    for (int e = sb + t; e < se; e += 256) {
        unsigned int pr = pairs[e];
        int l = pr >> 17;
        int r = atomicAdd(&cur[l], 1);  // LDS only
        srcs[r] = (int)(pr & 0x1FFFFu);
    }
}

// ---- hop: wave per node, 16-way edge-parallel, 8B lanes, padded lists ----
// srcs loads are nontemporal: 16MB single-use stream must not evict the
// 3.2MB u table from the 4MB per-XCD L2 (gather hit rate is the hop's floor).
template <int FINAL>
__global__ __launch_bounds__(256) void k_hop(const uint2* __restrict__ u8,
                                             const int* __restrict__ srcs,
                                             const int2* __restrict__ off2,
                                             const float* __restrict__ dinv,
                                             const float* __restrict__ bias,
                                             uint2* __restrict__ outh,
                                             float* __restrict__ outf, int N) {
    const int lane = threadIdx.x & 63;
    const int fp = lane & 3;
    const int ep = lane >> 2;
    const int n = blockIdx.x * 4 + (threadIdx.x >> 6);
    if (n >= N) return;  // wave-uniform
    const int2 oo = off2[n];
    const int beg = oo.x, end = oo.y;  // (end-beg) % 16 == 0, >= 16
    float ax = 0.f, ay = 0.f, az = 0.f, aw = 0.f;
    int e = beg + ep;
    for (; e + 16 < end; e += 32) {  // 2-deep: 32 edges per wave-iteration
        int s0 = __builtin_nontemporal_load(srcs + e);
        int s1 = __builtin_nontemporal_load(srcs + e + 16);
        uint2 q0 = u8[(size_t)s0 * 4 + fp];
        uint2 q1 = u8[(size_t)s1 * 4 + fp];
        float2 a0 = __half22float2(*(__half2*)&q0.x);
        float2 b0 = __half22float2(*(__half2*)&q0.y);
        float2 a1 = __half22float2(*(__half2*)&q1.x);
        float2 b1 = __half22float2(*(__half2*)&q1.y);
        ax += a0.x + a1.x;
        ay += a0.y + a1.y;
        az += b0.x + b1.x;
        aw += b0.y + b1.y;
    }
    if (e < end) {  // at most one leftover 16-chunk, fully lane-parallel
        int s0 = __builtin_nontemporal_load(srcs + e);
        uint2 q0 = u8[(size_t)s0 * 4 + fp];
        float2 a0 = __half22float2(*(__half2*)&q0.x);
        float2 b0 = __half22float2(*(__half2*)&q0.y);
        ax += a0.x;
        ay += a0.y;
        az += b0.x;
        aw += b0.y;
    }
#pragma unroll
    for (int d = 4; d <= 32; d <<= 1) {
        ax += __shfl_xor(ax, d);
        ay += __shfl_xor(ay, d);
        az += __shfl_xor(az, d);
        aw += __shfl_xor(aw, d);
    }
    if (ep != 0) return;
    float dn = dinv[n];
    if (!FINAL) {
        float s = dn * dn;
        __half2 h0 = __floats2half2_rn(s * ax, s * ay);
        __half2 h1 = __floats2half2_rn(s * az, s * aw);
        uint2 q;
        q.x = *(unsigned*)&h0;
        q.y = *(unsigned*)&h1;
        outh[(size_t)n * 4 + fp] = q;
    } else {
        float4 o;
        o.x = dn * ax + bias[4 * fp];
        o.y = dn * ay + bias[4 * fp + 1];
        o.z = dn * az + bias[4 * fp + 2];
        o.w = dn * aw + bias[4 * fp + 3];
        *(float4*)(outf + (size_t)n * DIMOUT + 4 * fp) = o;
    }
}

extern "C" void kernel_launch(void* const* d_in, const int* in_sizes, int n_in,
                              void* d_out, int out_size, void* d_ws, size_t ws_size,
                              hipStream_t stream) {
    const float* x = (const float*)d_in[0];
    const void* edges = d_in[1];
    const float* W = (const float*)d_in[2];
    const float* b = (const float*)d_in[3];
    float* out = (float*)d_out;

    const int N = in_sizes[0] / NF;  // 100000
    const int E = in_sizes[1] / 2;   // 3200000
    const int NBLK = (E + C1 - 1) / C1;
    const int NUSED = (N + NPBKT - 1) >> BSH;
    const int NBLK2 = (N + 255) / 256;

    char* ws = (char*)d_ws;
    size_t o = 0;
    auto alloc = [&](size_t bytes) -> void* {
        o = (o + 255) & ~(size_t)255;
        void* p = ws + o;
        o += bytes;
        return p;
    };
    int* lhistT = (int*)alloc((size_t)NBKT * NBLK * sizeof(int));
    int* lbase = (int*)alloc((size_t)NBKT * NBLK * sizeof(int));
    int* btot = (int*)alloc((size_t)NBKT * sizeof(int));
    int* gregion = (int*)alloc(((size_t)NBKT + 1) * sizeof(int));
    unsigned int* pairs = (unsigned int*)alloc((size_t)E * sizeof(unsigned int));
    int* srcs = (int*)alloc(((size_t)E + (size_t)16 * N + 256) * sizeof(int));
    int* nh = (int*)alloc((size_t)GSUB * N * sizeof(int));
    int2* lc = (int2*)alloc((size_t)N * sizeof(int2));
    int* btot2 = (int*)alloc((size_t)NBLK2 * sizeof(int));
    int* bbase2 = (int*)alloc((size_t)NBLK2 * sizeof(int));
    int2* off2 = (int2*)alloc((size_t)N * sizeof(int2));
    float* dinv = (float*)alloc((size_t)N * sizeof(float));
    __half* u0 = (__half*)alloc((size_t)(N + 1) * 16 * sizeof(__half));
    __half* u1 = (__half*)alloc((size_t)(N + 1) * 16 * sizeof(__half));
    (void)ws_size;
    (void)n_in;
    (void)out_size;

    k_lhist<<<NBLK, 256, 0, stream>>>(edges, lhistT, E, NBLK);
    k_cscan<<<NBKT, 256, 0, stream>>>(lhistT, lbase, btot, NBLK);
    k_gscan<<<1, NBKT, 0, stream>>>(btot, gregion);
    k_scatter<<<NBLK, 256, 0, stream>>>(edges, gregion, lbase, pairs, E, NBLK);
    k_nhist<<<NUSED * GSUB, 256, 0, stream>>>(pairs, gregion, nh, N);
    k_nscan<<<NBLK2, 256, 0, stream>>>(nh, dinv, lc, btot2, x, W, (__half2*)u0,
                                       (__half2*)u1, N);
    k_gscan2<<<1, 512, 0, stream>>>(btot2, bbase2, NBLK2);
    k_nfill<<<NBLK2, 256, 0, stream>>>(lc, bbase2, off2, srcs, N);
    k_nscatter<<<NUSED * GSUB, 256, 0, stream>>>(pairs, gregion, nh, off2, srcs, N);

    int hopgrid = (N + 3) / 4;
    k_hop<0><<<hopgrid, 256, 0, stream>>>((const uint2*)u0, srcs, off2, dinv, nullptr,
                                          (uint2*)u1, nullptr, N);
    k_hop<1><<<hopgrid, 256, 0, stream>>>((const uint2*)u1, srcs, off2, dinv, b,
                                          nullptr, out, N);
}

// Round 13
// 161.542 us; speedup vs baseline: 4.6957x; 1.1531x over previous
//
#include <hip/hip_runtime.h>
#include <hip/hip_fp16.h>

#define NF 14
#define DIMOUT 16
#define BSH 9        // 512 nodes per bucket
#define NPBKT 512
#define NBKT 256     // bucket count (used: ceil(N/512) = 196)
#define C1 4096      // edges per block in bucket passes
#define GSUB 8       // subchunks per bucket in node-level passes

// int64 edge buffer <=> odd 32-bit words (high halves) all zero (ids < 2^31)
__device__ __forceinline__ bool detect64(const int* e32) {
    bool is64 = true;
#pragma unroll
    for (int i = 1; i < 64; i += 2) is64 &= (e32[i] == 0);
    return is64;
}

// ---- per-block bucket histogram (transposed write); 16B paired loads ----
__global__ __launch_bounds__(256) void k_lhist(const void* __restrict__ edges,
                                               int* __restrict__ lhistT, int E, int NBLK) {
    __shared__ int h[NBKT];
    const int t = threadIdx.x;
    h[t] = 0;
    __syncthreads();
    const int* e32 = (const int*)edges;
    const long long* e64 = (const long long*)edges;
    const bool is64 = detect64(e32);
    const int base = blockIdx.x * C1;
    const int cnt = min(C1, E - base);  // always even (E, C1 even)
    if (is64) {
        const longlong2* p2 = (const longlong2*)(e64 + (size_t)E + base);
        for (int j = 2 * t; j < cnt; j += 512) {
            longlong2 v = p2[j >> 1];
            atomicAdd(&h[((int)v.x) >> BSH], 1);
            atomicAdd(&h[((int)v.y) >> BSH], 1);
        }
    } else {
        const int2* p2 = (const int2*)(e32 + (size_t)E + base);
        for (int j = 2 * t; j < cnt; j += 512) {
            int2 v = p2[j >> 1];
            atomicAdd(&h[v.x >> BSH], 1);
            atomicAdd(&h[v.y >> BSH], 1);
        }
    }
    __syncthreads();
    lhistT[(size_t)t * NBLK + blockIdx.x] = h[t];
}

// ---- per-bucket scan over blocks ----
__global__ __launch_bounds__(256) void k_cscan(const int* __restrict__ lhistT,
                                               int* __restrict__ lbase,
                                               int* __restrict__ btot, int NBLK) {
    const int b = blockIdx.x;
    const int t = threadIdx.x;
    const int IPT = (NBLK + 255) / 256;
    int v[8];
    int s = 0;
    for (int k = 0; k < IPT; ++k) {
        int j = t * IPT + k;
        int x = (j < NBLK) ? lhistT[(size_t)b * NBLK + j] : 0;
        v[k] = x;
        s += x;
    }
    __shared__ int sm[256];
    sm[t] = s;
    __syncthreads();
    for (int d = 1; d < 256; d <<= 1) {
        int u = (t >= d) ? sm[t - d] : 0;
        __syncthreads();
        sm[t] += u;
        __syncthreads();
    }
    int run = sm[t] - s;
    for (int k = 0; k < IPT; ++k) {
        int j = t * IPT + k;
        if (j < NBLK) {
            lbase[(size_t)b * NBLK + j] = run;
            run += v[k];
        }
    }
    if (t == 255) btot[b] = sm[255];
}

// ---- scan bucket totals -> regions ----
__global__ __launch_bounds__(NBKT) void k_gscan(const int* __restrict__ btot,
                                                int* __restrict__ gregion) {
    __shared__ int sm[NBKT];
    int t = threadIdx.x;
    int v = btot[t];
    sm[t] = v;
    __syncthreads();
    for (int d = 1; d < NBKT; d <<= 1) {
        int u = (t >= d) ? sm[t - d] : 0;
        __syncthreads();
        sm[t] += u;
        __syncthreads();
    }
    gregion[t] = sm[t] - v;
    if (t == NBKT - 1) gregion[NBKT] = sm[t];
}

// ---- bucket scatter: block-local LDS counting sort, runs at exact bases ----
// packed entry: (dst & 511) << 17 | src ; 16B paired edge loads
__global__ __launch_bounds__(256) void k_scatter(const void* __restrict__ edges,
                                                 const int* __restrict__ gregion,
                                                 const int* __restrict__ lbase,
                                                 unsigned int* __restrict__ pairs,
                                                 int E, int NBLK) {
    __shared__ unsigned int raw[C1];
    __shared__ unsigned int srt[C1];
    __shared__ unsigned short bkt[C1];
    __shared__ unsigned char sbk[C1];
    __shared__ int hist[NBKT], scn[NBKT], gb[NBKT], cur[NBKT];
    const int* e32 = (const int*)edges;
    const long long* e64 = (const long long*)edges;
    const bool is64 = detect64(e32);
    const int t = threadIdx.x;
    const int base = blockIdx.x * C1;
    const int cnt = min(C1, E - base);  // always even
    hist[t] = 0;
    cur[t] = 0;
    __syncthreads();
    for (int j = 2 * t; j < cnt; j += 512) {
        int s0, s1, d0, d1;
        if (is64) {
            longlong2 vs = *(const longlong2*)(e64 + (size_t)base + j);
            longlong2 vd = *(const longlong2*)(e64 + (size_t)E + base + j);
            s0 = (int)vs.x;
            s1 = (int)vs.y;
            d0 = (int)vd.x;
            d1 = (int)vd.y;
        } else {
            int2 vs = *(const int2*)(e32 + (size_t)base + j);
            int2 vd = *(const int2*)(e32 + (size_t)E + base + j);
            s0 = vs.x;
            s1 = vs.y;
            d0 = vd.x;
            d1 = vd.y;
        }
        int b0 = d0 >> BSH, b1 = d1 >> BSH;
        raw[j] = (unsigned int)s0 | ((unsigned int)(d0 & (NPBKT - 1)) << 17);
        raw[j + 1] = (unsigned int)s1 | ((unsigned int)(d1 & (NPBKT - 1)) << 17);
        bkt[j] = (unsigned short)b0;
        bkt[j + 1] = (unsigned short)b1;
        atomicAdd(&hist[b0], 1);
        atomicAdd(&hist[b1], 1);
    }
    __syncthreads();
    int v = hist[t];
    scn[t] = v;
    __syncthreads();
    for (int d = 1; d < NBKT; d <<= 1) {
        int u = (t >= d) ? scn[t - d] : 0;
        __syncthreads();
        scn[t] += u;
        __syncthreads();
    }
    int ex = scn[t] - v;
    gb[t] = gregion[t] + lbase[(size_t)t * NBLK + blockIdx.x];
    __syncthreads();
    scn[t] = ex;
    __syncthreads();
    for (int j = t; j < cnt; j += 256) {
        int b = bkt[j];
        int r = atomicAdd(&cur[b], 1);
        int pos = scn[b] + r;
        srt[pos] = raw[j];
        sbk[pos] = (unsigned char)b;
    }
    __syncthreads();
    for (int j = t; j < cnt; j += 256) {
        int b = sbk[j];
        pairs[gb[b] + (j - scn[b])] = srt[j];
    }
}

// ---- node-level histogram per (bucket, subchunk); g-major layout ----
__global__ __launch_bounds__(256) void k_nhist(const unsigned int* __restrict__ pairs,
                                               const int* __restrict__ gregion,
                                               int* __restrict__ nh, int N) {
    const int b = blockIdx.x >> 3;
    const int g = blockIdx.x & 7;
    const int e0 = gregion[b], e1 = gregion[b + 1];
    const int L = e1 - e0;
    const int sb = e0 + ((L * g) >> 3);
    const int se = e0 + ((L * (g + 1)) >> 3);
    __shared__ int h[NPBKT];
    const int t = threadIdx.x;
    h[t] = 0;
    h[t + 256] = 0;
    __syncthreads();
    for (int e = sb + t; e < se; e += 256) atomicAdd(&h[pairs[e] >> 17], 1);
    __syncthreads();
    const int nbase = b << BSH;
    for (int l = t; l < NPBKT; l += 256) {
        int n = nbase + l;
        if (n < N) nh[(size_t)g * N + n] = h[l];
    }
}

// ---- per-node scan over subchunks + block scan of padded degrees ----
__global__ __launch_bounds__(256) void k_nscan(int* __restrict__ nh,
                                               float* __restrict__ dinv,
                                               int2* __restrict__ lc,
                                               int* __restrict__ btot2, int N) {
    const int t = threadIdx.x;
    const int n = blockIdx.x * 256 + t;
    int c = 0, p = 0;
    if (n < N) {
        int v[GSUB];
        int ex = 0;
#pragma unroll
        for (int g = 0; g < GSUB; ++g) v[g] = nh[(size_t)g * N + n];
#pragma unroll
        for (int g = 0; g < GSUB; ++g) {
            int vv = v[g];
            nh[(size_t)g * N + n] = ex;  // counts -> exclusive bases (in place)
            ex += vv;
        }
        c = ex;
        p = (c + 16) & ~15;  // self-loop + pad to multiple of 16
        dinv[n] = rsqrtf((float)(c + 1));
    }
    __shared__ int sm[256];
    sm[t] = p;
    __syncthreads();
    for (int d = 1; d < 256; d <<= 1) {
        int u = (t >= d) ? sm[t - d] : 0;
        __syncthreads();
        sm[t] += u;
        __syncthreads();
    }
    if (n < N) lc[n] = make_int2(sm[t] - p, c);  // (local offset, degree)
    if (t == 255) btot2[blockIdx.x] = sm[255];
}

// ---- scan per-block padded totals ----
__global__ __launch_bounds__(512) void k_gscan2(const int* __restrict__ btot2,
                                                int* __restrict__ bbase2, int nb) {
    __shared__ int sm[512];
    int t = threadIdx.x;
    int v = (t < nb) ? btot2[t] : 0;
    sm[t] = v;
    __syncthreads();
    for (int d = 1; d < 512; d <<= 1) {
        int u = (t >= d) ? sm[t - d] : 0;
        __syncthreads();
        sm[t] += u;
        __syncthreads();
    }
    if (t < nb) bbase2[t] = sm[t] - v;
}

// ---- finalize offsets, self-loop entries, sentinel pads ----
__global__ __launch_bounds__(256) void k_nfill(const int2* __restrict__ lc,
                                               const int* __restrict__ bbase2,
                                               int2* __restrict__ off2,
                                               int* __restrict__ srcs, int N) {
    const int n = blockIdx.x * 256 + threadIdx.x;
    if (n >= N) return;
    int2 l = lc[n];
    const int off = bbase2[blockIdx.x] + l.x;
    const int c = l.y;
    const int p = (c + 16) & ~15;
    off2[n] = make_int2(off, off + p);
    srcs[off] = n;  // self loop at slot 0
    for (int k = c + 1; k < p; ++k) srcs[off + k] = N;  // sentinel pad
}

// ---- node-level scatter per (bucket, subchunk) at precomputed bases ----
__global__ __launch_bounds__(256) void k_nscatter(const unsigned int* __restrict__ pairs,
                                                  const int* __restrict__ gregion,
                                                  const int* __restrict__ nh,
                                                  const int2* __restrict__ off2,
                                                  int* __restrict__ srcs, int N) {
    const int b = blockIdx.x >> 3;
    const int g = blockIdx.x & 7;
    const int e0 = gregion[b], e1 = gregion[b + 1];
    const int L = e1 - e0;
    const int sb = e0 + ((L * g) >> 3);
    const int se = e0 + ((L * (g + 1)) >> 3);
    __shared__ int cur[NPBKT];
    const int t = threadIdx.x;
    const int nbase = b << BSH;
    for (int l = t; l < NPBKT; l += 256) {
        int n = nbase + l;
        if (n < N) cur[l] = off2[n].x + 1 + nh[(size_t)g * N + n];
    }
    __syncthreads();
    for (int e = sb + t; e < se; e += 256) {
        unsigned int pr = pairs[e];
        int l = pr >> 17;
        int r = atomicAdd(&cur[l], 1);  // LDS only
        srcs[r] = (int)(pr & 0x1FFFFu);
    }
}

// ---- prep: u0[n] = fp16( dinv[n] * (x[n] @ W^T) ); zero sentinel rows ----
__global__ __launch_bounds__(256) void k_prep(const float* __restrict__ x,
                                              const float* __restrict__ dinv,
                                              const float* __restrict__ Wg,
                                              __half2* __restrict__ u0,
                                              __half2* __restrict__ u1, int N) {
    __shared__ float Wl[DIMOUT * NF];
    int t = threadIdx.x;
    if (t < DIMOUT * NF) Wl[t] = Wg[t];
    __syncthreads();
    if (blockIdx.x == 0 && t < 8) {  // zero sentinel rows (src == N)
        u0[(size_t)N * 8 + t] = __floats2half2_rn(0.f, 0.f);
        u1[(size_t)N * 8 + t] = __floats2half2_rn(0.f, 0.f);
    }
    int n = blockIdx.x * 256 + t;
    if (n >= N) return;
    float xr[NF];
    const float2* xr2 = (const float2*)(x + (size_t)n * NF);
#pragma unroll
    for (int k = 0; k < 7; ++k) {
        float2 v = xr2[k];
        xr[2 * k] = v.x;
        xr[2 * k + 1] = v.y;
    }
    float dn = dinv[n];
#pragma unroll
    for (int q = 0; q < 8; ++q) {
        float r0 = 0.f, r1 = 0.f;
#pragma unroll
        for (int f = 0; f < NF; ++f) {
            r0 += xr[f] * Wl[(2 * q) * NF + f];
            r1 += xr[f] * Wl[(2 * q + 1) * NF + f];
        }
        u0[(size_t)n * 8 + q] = __floats2half2_rn(dn * r0, dn * r1);
    }
}

// ---- hop: wave per node, 16-way edge-parallel, 8B lanes, padded lists ----
template <int FINAL>
__global__ __launch_bounds__(256) void k_hop(const uint2* __restrict__ u8,
                                             const int* __restrict__ srcs,
                                             const int2* __restrict__ off2,
                                             const float* __restrict__ dinv,
                                             const float* __restrict__ bias,
                                             uint2* __restrict__ outh,
                                             float* __restrict__ outf, int N) {
    const int lane = threadIdx.x & 63;
    const int fp = lane & 3;
    const int ep = lane >> 2;
    const int n = blockIdx.x * 4 + (threadIdx.x >> 6);
    if (n >= N) return;  // wave-uniform
    const int2 oo = off2[n];
    const int beg = oo.x, end = oo.y;  // (end-beg) % 16 == 0, >= 16
    float ax = 0.f, ay = 0.f, az = 0.f, aw = 0.f;
    int e = beg + ep;
    for (; e + 16 < end; e += 32) {  // 2-deep: 32 edges per wave-iteration
        int s0 = srcs[e];
        int s1 = srcs[e + 16];
        uint2 q0 = u8[(size_t)s0 * 4 + fp];
        uint2 q1 = u8[(size_t)s1 * 4 + fp];
        float2 a0 = __half22float2(*(__half2*)&q0.x);
        float2 b0 = __half22float2(*(__half2*)&q0.y);
        float2 a1 = __half22float2(*(__half2*)&q1.x);
        float2 b1 = __half22float2(*(__half2*)&q1.y);
        ax += a0.x + a1.x;
        ay += a0.y + a1.y;
        az += b0.x + b1.x;
        aw += b0.y + b1.y;
    }
    if (e < end) {  // at most one leftover 16-chunk, fully lane-parallel
        int s0 = srcs[e];
        uint2 q0 = u8[(size_t)s0 * 4 + fp];
        float2 a0 = __half22float2(*(__half2*)&q0.x);
        float2 b0 = __half22float2(*(__half2*)&q0.y);
        ax += a0.x;
        ay += a0.y;
        az += b0.x;
        aw += b0.y;
    }
#pragma unroll
    for (int d = 4; d <= 32; d <<= 1) {
        ax += __shfl_xor(ax, d);
        ay += __shfl_xor(ay, d);
        az += __shfl_xor(az, d);
        aw += __shfl_xor(aw, d);
    }
    if (ep != 0) return;
    float dn = dinv[n];
    if (!FINAL) {
        float s = dn * dn;
        __half2 h0 = __floats2half2_rn(s * ax, s * ay);
        __half2 h1 = __floats2half2_rn(s * az, s * aw);
        uint2 q;
        q.x = *(unsigned*)&h0;
        q.y = *(unsigned*)&h1;
        outh[(size_t)n * 4 + fp] = q;
    } else {
        float4 o;
        o.x = dn * ax + bias[4 * fp];
        o.y = dn * ay + bias[4 * fp + 1];
        o.z = dn * az + bias[4 * fp + 2];
        o.w = dn * aw + bias[4 * fp + 3];
        *(float4*)(outf + (size_t)n * DIMOUT + 4 * fp) = o;
    }
}

extern "C" void kernel_launch(void* const* d_in, const int* in_sizes, int n_in,
                              void* d_out, int out_size, void* d_ws, size_t ws_size,
                              hipStream_t stream) {
    const float* x = (const float*)d_in[0];
    const void* edges = d_in[1];
    const float* W = (const float*)d_in[2];
    const float* b = (const float*)d_in[3];
    float* out = (float*)d_out;

    const int N = in_sizes[0] / NF;  // 100000
    const int E = in_sizes[1] / 2;   // 3200000
    const int NBLK = (E + C1 - 1) / C1;
    const int NUSED = (N + NPBKT - 1) >> BSH;
    const int NBLK2 = (N + 255) / 256;

    char* ws = (char*)d_ws;
    size_t o = 0;
    auto alloc = [&](size_t bytes) -> void* {
        o = (o + 255) & ~(size_t)255;
        void* p = ws + o;
        o += bytes;
        return p;
    };
    int* lhistT = (int*)alloc((size_t)NBKT * NBLK * sizeof(int));
    int* lbase = (int*)alloc((size_t)NBKT * NBLK * sizeof(int));
    int* btot = (int*)alloc((size_t)NBKT * sizeof(int));
    int* gregion = (int*)alloc(((size_t)NBKT + 1) * sizeof(int));
    unsigned int* pairs = (unsigned int*)alloc((size_t)E * sizeof(unsigned int));
    int* srcs = (int*)alloc(((size_t)E + (size_t)16 * N + 256) * sizeof(int));
    int* nh = (int*)alloc((size_t)GSUB * N * sizeof(int));
    int2* lc = (int2*)alloc((size_t)N * sizeof(int2));
    int* btot2 = (int*)alloc((size_t)NBLK2 * sizeof(int));
    int* bbase2 = (int*)alloc((size_t)NBLK2 * sizeof(int));
    int2* off2 = (int2*)alloc((size_t)N * sizeof(int2));
    float* dinv = (float*)alloc((size_t)N * sizeof(float));
    __half* u0 = (__half*)alloc((size_t)(N + 1) * 16 * sizeof(__half));
    __half* u1 = (__half*)alloc((size_t)(N + 1) * 16 * sizeof(__half));
    (void)ws_size;
    (void)n_in;
    (void)out_size;

    k_lhist<<<NBLK, 256, 0, stream>>>(edges, lhistT, E, NBLK);
    k_cscan<<<NBKT, 256, 0, stream>>>(lhistT, lbase, btot, NBLK);
    k_gscan<<<1, NBKT, 0, stream>>>(btot, gregion);
    k_scatter<<<NBLK, 256, 0, stream>>>(edges, gregion, lbase, pairs, E, NBLK);
    k_nhist<<<NUSED * GSUB, 256, 0, stream>>>(pairs, gregion, nh, N);
    k_nscan<<<NBLK2, 256, 0, stream>>>(nh, dinv, lc, btot2, N);
    k_prep<<<NBLK2, 256, 0, stream>>>(x, dinv, W, (__half2*)u0, (__half2*)u1, N);
    k_gscan2<<<1, 512, 0, stream>>>(btot2, bbase2, NBLK2);
    k_nfill<<<NBLK2, 256, 0, stream>>>(lc, bbase2, off2, srcs, N);
    k_nscatter<<<NUSED * GSUB, 256, 0, stream>>>(pairs, gregion, nh, off2, srcs, N);

    int hopgrid = (N + 3) / 4;
    k_hop<0><<<hopgrid, 256, 0, stream>>>((const uint2*)u0, srcs, off2, dinv, nullptr,
                                          (uint2*)u1, nullptr, N);
    k_hop<1><<<hopgrid, 256, 0, stream>>>((const uint2*)u1, srcs, off2, dinv, b,
                                          nullptr, out, N);
}

// Round 14
// 152.578 us; speedup vs baseline: 4.9716x; 1.0588x over previous
//
#include <hip/hip_runtime.h>
#include <hip/hip_fp16.h>

#define NF 14
#define DIMOUT 16
#define BSH 9        // 512 nodes per bucket
#define NPBKT 512
#define NBKT 256     // bucket count (used: ceil(N/512) = 196)
#define C1 4096      // edges per block in bucket passes
#define GSUB 8       // subchunks per bucket in node-level passes

// int64 edge buffer <=> odd 32-bit words (high halves) all zero (ids < 2^31)
__device__ __forceinline__ bool detect64(const int* e32) {
    bool is64 = true;
#pragma unroll
    for (int i = 1; i < 64; i += 2) is64 &= (e32[i] == 0);
    return is64;
}

// ---- per-block bucket histogram (transposed write); 16B paired loads ----
__global__ __launch_bounds__(256) void k_lhist(const void* __restrict__ edges,
                                               int* __restrict__ lhistT, int E, int NBLK) {
    __shared__ int h[NBKT];
    const int t = threadIdx.x;
    h[t] = 0;
    __syncthreads();
    const int* e32 = (const int*)edges;
    const long long* e64 = (const long long*)edges;
    const bool is64 = detect64(e32);
    const int base = blockIdx.x * C1;
    const int cnt = min(C1, E - base);  // always even (E, C1 even)
    if (is64) {
        const longlong2* p2 = (const longlong2*)(e64 + (size_t)E + base);
        for (int j = 2 * t; j < cnt; j += 512) {
            longlong2 v = p2[j >> 1];
            atomicAdd(&h[((int)v.x) >> BSH], 1);
            atomicAdd(&h[((int)v.y) >> BSH], 1);
        }
    } else {
        const int2* p2 = (const int2*)(e32 + (size_t)E + base);
        for (int j = 2 * t; j < cnt; j += 512) {
            int2 v = p2[j >> 1];
            atomicAdd(&h[v.x >> BSH], 1);
            atomicAdd(&h[v.y >> BSH], 1);
        }
    }
    __syncthreads();
    lhistT[(size_t)t * NBLK + blockIdx.x] = h[t];
}

// ---- per-bucket scan over blocks ----
__global__ __launch_bounds__(256) void k_cscan(const int* __restrict__ lhistT,
                                               int* __restrict__ lbase,
                                               int* __restrict__ btot, int NBLK) {
    const int b = blockIdx.x;
    const int t = threadIdx.x;
    const int IPT = (NBLK + 255) / 256;
    int v[8];
    int s = 0;
    for (int k = 0; k < IPT; ++k) {
        int j = t * IPT + k;
        int x = (j < NBLK) ? lhistT[(size_t)b * NBLK + j] : 0;
        v[k] = x;
        s += x;
    }
    __shared__ int sm[256];
    sm[t] = s;
    __syncthreads();
    for (int d = 1; d < 256; d <<= 1) {
        int u = (t >= d) ? sm[t - d] : 0;
        __syncthreads();
        sm[t] += u;
        __syncthreads();
    }
    int run = sm[t] - s;
    for (int k = 0; k < IPT; ++k) {
        int j = t * IPT + k;
        if (j < NBLK) {
            lbase[(size_t)b * NBLK + j] = run;
            run += v[k];
        }
    }
    if (t == 255) btot[b] = sm[255];
}

// ---- scan bucket totals -> regions ----
__global__ __launch_bounds__(NBKT) void k_gscan(const int* __restrict__ btot,
                                                int* __restrict__ gregion) {
    __shared__ int sm[NBKT];
    int t = threadIdx.x;
    int v = btot[t];
    sm[t] = v;
    __syncthreads();
    for (int d = 1; d < NBKT; d <<= 1) {
        int u = (t >= d) ? sm[t - d] : 0;
        __syncthreads();
        sm[t] += u;
        __syncthreads();
    }
    gregion[t] = sm[t] - v;
    if (t == NBKT - 1) gregion[NBKT] = sm[t];
}

// ---- bucket scatter: block-local LDS counting sort, runs at exact bases ----
// packed entry: (dst & 511) << 17 | src ; 16B paired edge loads
__global__ __launch_bounds__(256) void k_scatter(const void* __restrict__ edges,
                                                 const int* __restrict__ gregion,
                                                 const int* __restrict__ lbase,
                                                 unsigned int* __restrict__ pairs,
                                                 int E, int NBLK) {
    __shared__ unsigned int raw[C1];
    __shared__ unsigned int srt[C1];
    __shared__ unsigned short bkt[C1];
    __shared__ unsigned char sbk[C1];
    __shared__ int hist[NBKT], scn[NBKT], gb[NBKT], cur[NBKT];
    const int* e32 = (const int*)edges;
    const long long* e64 = (const long long*)edges;
    const bool is64 = detect64(e32);
    const int t = threadIdx.x;
    const int base = blockIdx.x * C1;
    const int cnt = min(C1, E - base);  // always even
    hist[t] = 0;
    cur[t] = 0;
    __syncthreads();
    for (int j = 2 * t; j < cnt; j += 512) {
        int s0, s1, d0, d1;
        if (is64) {
            longlong2 vs = *(const longlong2*)(e64 + (size_t)base + j);
            longlong2 vd = *(const longlong2*)(e64 + (size_t)E + base + j);
            s0 = (int)vs.x;
            s1 = (int)vs.y;
            d0 = (int)vd.x;
            d1 = (int)vd.y;
        } else {
            int2 vs = *(const int2*)(e32 + (size_t)base + j);
            int2 vd = *(const int2*)(e32 + (size_t)E + base + j);
            s0 = vs.x;
            s1 = vs.y;
            d0 = vd.x;
            d1 = vd.y;
        }
        int b0 = d0 >> BSH, b1 = d1 >> BSH;
        raw[j] = (unsigned int)s0 | ((unsigned int)(d0 & (NPBKT - 1)) << 17);
        raw[j + 1] = (unsigned int)s1 | ((unsigned int)(d1 & (NPBKT - 1)) << 17);
        bkt[j] = (unsigned short)b0;
        bkt[j + 1] = (unsigned short)b1;
        atomicAdd(&hist[b0], 1);
        atomicAdd(&hist[b1], 1);
    }
    __syncthreads();
    int v = hist[t];
    scn[t] = v;
    __syncthreads();
    for (int d = 1; d < NBKT; d <<= 1) {
        int u = (t >= d) ? scn[t - d] : 0;
        __syncthreads();
        scn[t] += u;
        __syncthreads();
    }
    int ex = scn[t] - v;
    gb[t] = gregion[t] + lbase[(size_t)t * NBLK + blockIdx.x];
    __syncthreads();
    scn[t] = ex;
    __syncthreads();
    for (int j = t; j < cnt; j += 256) {
        int b = bkt[j];
        int r = atomicAdd(&cur[b], 1);
        int pos = scn[b] + r;
        srt[pos] = raw[j];
        sbk[pos] = (unsigned char)b;
    }
    __syncthreads();
    for (int j = t; j < cnt; j += 256) {
        int b = sbk[j];
        pairs[gb[b] + (j - scn[b])] = srt[j];
    }
}

// ---- node-level histogram per (bucket, subchunk); g-major layout ----
__global__ __launch_bounds__(256) void k_nhist(const unsigned int* __restrict__ pairs,
                                               const int* __restrict__ gregion,
                                               int* __restrict__ nh, int N) {
    const int b = blockIdx.x >> 3;
    const int g = blockIdx.x & 7;
    const int e0 = gregion[b], e1 = gregion[b + 1];
    const int L = e1 - e0;
    const int sb = e0 + ((L * g) >> 3);
    const int se = e0 + ((L * (g + 1)) >> 3);
    __shared__ int h[NPBKT];
    const int t = threadIdx.x;
    h[t] = 0;
    h[t + 256] = 0;
    __syncthreads();
    for (int e = sb + t; e < se; e += 256) atomicAdd(&h[pairs[e] >> 17], 1);
    __syncthreads();
    const int nbase = b << BSH;
    for (int l = t; l < NPBKT; l += 256) {
        int n = nbase + l;
        if (n < N) nh[(size_t)g * N + n] = h[l];
    }
}

// ---- per-node scan over subchunks + block scan of padded degrees ----
__global__ __launch_bounds__(256) void k_nscan(int* __restrict__ nh,
                                               float* __restrict__ dinv,
                                               int2* __restrict__ lc,
                                               int* __restrict__ btot2, int N) {
    const int t = threadIdx.x;
    const int n = blockIdx.x * 256 + t;
    int c = 0, p = 0;
    if (n < N) {
        int v[GSUB];
        int ex = 0;
#pragma unroll
        for (int g = 0; g < GSUB; ++g) v[g] = nh[(size_t)g * N + n];
#pragma unroll
        for (int g = 0; g < GSUB; ++g) {
            int vv = v[g];
            nh[(size_t)g * N + n] = ex;  // counts -> exclusive bases (in place)
            ex += vv;
        }
        c = ex;
        p = (c + 16) & ~15;  // self-loop + pad to multiple of 16
        dinv[n] = rsqrtf((float)(c + 1));
    }
    __shared__ int sm[256];
    sm[t] = p;
    __syncthreads();
    for (int d = 1; d < 256; d <<= 1) {
        int u = (t >= d) ? sm[t - d] : 0;
        __syncthreads();
        sm[t] += u;
        __syncthreads();
    }
    if (n < N) lc[n] = make_int2(sm[t] - p, c);  // (local offset, degree)
    if (t == 255) btot2[blockIdx.x] = sm[255];
}

// ---- scan per-block padded totals ----
__global__ __launch_bounds__(512) void k_gscan2(const int* __restrict__ btot2,
                                                int* __restrict__ bbase2, int nb) {
    __shared__ int sm[512];
    int t = threadIdx.x;
    int v = (t < nb) ? btot2[t] : 0;
    sm[t] = v;
    __syncthreads();
    for (int d = 1; d < 512; d <<= 1) {
        int u = (t >= d) ? sm[t - d] : 0;
        __syncthreads();
        sm[t] += u;
        __syncthreads();
    }
    if (t < nb) bbase2[t] = sm[t] - v;
}

// ---- finalize offsets, self-loop entries, sentinel pads ----
__global__ __launch_bounds__(256) void k_nfill(const int2* __restrict__ lc,
                                               const int* __restrict__ bbase2,
                                               int2* __restrict__ off2,
                                               int* __restrict__ srcs, int N) {
    const int n = blockIdx.x * 256 + threadIdx.x;
    if (n >= N) return;
    int2 l = lc[n];
    const int off = bbase2[blockIdx.x] + l.x;
    const int c = l.y;
    const int p = (c + 16) & ~15;
    off2[n] = make_int2(off, off + p);
    srcs[off] = n;  // self loop at slot 0
    for (int k = c + 1; k < p; ++k) srcs[off + k] = N;  // sentinel pad
}

// ---- node-level scatter per (bucket, subchunk) at precomputed bases ----
__global__ __launch_bounds__(256) void k_nscatter(const unsigned int* __restrict__ pairs,
                                                  const int* __restrict__ gregion,
                                                  const int* __restrict__ nh,
                                                  const int2* __restrict__ off2,
                                                  int* __restrict__ srcs, int N) {
    const int b = blockIdx.x >> 3;
    const int g = blockIdx.x & 7;
    const int e0 = gregion[b], e1 = gregion[b + 1];
    const int L = e1 - e0;
    const int sb = e0 + ((L * g) >> 3);
    const int se = e0 + ((L * (g + 1)) >> 3);
    __shared__ int cur[NPBKT];
    const int t = threadIdx.x;
    const int nbase = b << BSH;
    for (int l = t; l < NPBKT; l += 256) {
        int n = nbase + l;
        if (n < N) cur[l] = off2[n].x + 1 + nh[(size_t)g * N + n];
    }
    __syncthreads();
    for (int e = sb + t; e < se; e += 256) {
        unsigned int pr = pairs[e];
        int l = pr >> 17;
        int r = atomicAdd(&cur[l], 1);  // LDS only
        srcs[r] = (int)(pr & 0x1FFFFu);
    }
}

// ---- prep: u0[n] = fp16( dinv[n] * (x[n] @ W^T) ); zero sentinel rows ----
__global__ __launch_bounds__(256) void k_prep(const float* __restrict__ x,
                                              const float* __restrict__ dinv,
                                              const float* __restrict__ Wg,
                                              __half2* __restrict__ u0,
                                              __half2* __restrict__ u1, int N) {
    __shared__ float Wl[DIMOUT * NF];
    int t = threadIdx.x;
    if (t < DIMOUT * NF) Wl[t] = Wg[t];
    __syncthreads();
    if (blockIdx.x == 0 && t < 8) {  // zero sentinel rows (src == N)
        u0[(size_t)N * 8 + t] = __floats2half2_rn(0.f, 0.f);
        u1[(size_t)N * 8 + t] = __floats2half2_rn(0.f, 0.f);
    }
    int n = blockIdx.x * 256 + t;
    if (n >= N) return;
    float xr[NF];
    const float2* xr2 = (const float2*)(x + (size_t)n * NF);
#pragma unroll
    for (int k = 0; k < 7; ++k) {
        float2 v = xr2[k];
        xr[2 * k] = v.x;
        xr[2 * k + 1] = v.y;
    }
    float dn = dinv[n];
#pragma unroll
    for (int q = 0; q < 8; ++q) {
        float r0 = 0.f, r1 = 0.f;
#pragma unroll
        for (int f = 0; f < NF; ++f) {
            r0 += xr[f] * Wl[(2 * q) * NF + f];
            r1 += xr[f] * Wl[(2 * q + 1) * NF + f];
        }
        u0[(size_t)n * 8 + q] = __floats2half2_rn(dn * r0, dn * r1);
    }
}

// ---- hop: grid-stride, wave per node, 16-way edge-parallel, 8B lanes ----
// 2048 blocks = 8192 waves = 8 waves/SIMD resident (max occupancy); each
// wave sweeps ~12 nodes so slots stay warm instead of re-dispatching blocks.
template <int FINAL>
__global__ __launch_bounds__(256) void k_hop(const uint2* __restrict__ u8,
                                             const int* __restrict__ srcs,
                                             const int2* __restrict__ off2,
                                             const float* __restrict__ dinv,
                                             const float* __restrict__ bias,
                                             uint2* __restrict__ outh,
                                             float* __restrict__ outf, int N) {
    const int lane = threadIdx.x & 63;
    const int fp = lane & 3;
    const int ep = lane >> 2;
    const int wid = threadIdx.x >> 6;
    float4 breg = make_float4(0.f, 0.f, 0.f, 0.f);
    if (FINAL) breg = *(const float4*)(bias + 4 * fp);
    const int stride = gridDim.x * 4;
    for (int n = blockIdx.x * 4 + wid; n < N; n += stride) {
        const int2 oo = off2[n];
        const int beg = oo.x, end = oo.y;  // (end-beg) % 16 == 0, >= 16
        float ax = 0.f, ay = 0.f, az = 0.f, aw = 0.f;
        int e = beg + ep;
        for (; e + 16 < end; e += 32) {  // 2-deep: 32 edges per wave-iteration
            int s0 = srcs[e];
            int s1 = srcs[e + 16];
            uint2 q0 = u8[(size_t)s0 * 4 + fp];
            uint2 q1 = u8[(size_t)s1 * 4 + fp];
            float2 a0 = __half22float2(*(__half2*)&q0.x);
            float2 b0 = __half22float2(*(__half2*)&q0.y);
            float2 a1 = __half22float2(*(__half2*)&q1.x);
            float2 b1 = __half22float2(*(__half2*)&q1.y);
            ax += a0.x + a1.x;
            ay += a0.y + a1.y;
            az += b0.x + b1.x;
            aw += b0.y + b1.y;
        }
        if (e < end) {  // at most one leftover 16-chunk, fully lane-parallel
            int s0 = srcs[e];
            uint2 q0 = u8[(size_t)s0 * 4 + fp];
            float2 a0 = __half22float2(*(__half2*)&q0.x);
            float2 b0 = __half22float2(*(__half2*)&q0.y);
            ax += a0.x;
            ay += a0.y;
            az += b0.x;
            aw += b0.y;
        }
#pragma unroll
        for (int d = 4; d <= 32; d <<= 1) {
            ax += __shfl_xor(ax, d);
            ay += __shfl_xor(ay, d);
            az += __shfl_xor(az, d);
            aw += __shfl_xor(aw, d);
        }
        if (ep == 0) {
            float dn = dinv[n];
            if (!FINAL) {
                float s = dn * dn;
                __half2 h0 = __floats2half2_rn(s * ax, s * ay);
                __half2 h1 = __floats2half2_rn(s * az, s * aw);
                uint2 q;
                q.x = *(unsigned*)&h0;
                q.y = *(unsigned*)&h1;
                outh[(size_t)n * 4 + fp] = q;
            } else {
                float4 o;
                o.x = dn * ax + breg.x;
                o.y = dn * ay + breg.y;
                o.z = dn * az + breg.z;
                o.w = dn * aw + breg.w;
                *(float4*)(outf + (size_t)n * DIMOUT + 4 * fp) = o;
            }
        }
    }
}

extern "C" void kernel_launch(void* const* d_in, const int* in_sizes, int n_in,
                              void* d_out, int out_size, void* d_ws, size_t ws_size,
                              hipStream_t stream) {
    const float* x = (const float*)d_in[0];
    const void* edges = d_in[1];
    const float* W = (const float*)d_in[2];
    const float* b = (const float*)d_in[3];
    float* out = (float*)d_out;

    const int N = in_sizes[0] / NF;  // 100000
    const int E = in_sizes[1] / 2;   // 3200000
    const int NBLK = (E + C1 - 1) / C1;
    const int NUSED = (N + NPBKT - 1) >> BSH;
    const int NBLK2 = (N + 255) / 256;

    char* ws = (char*)d_ws;
    size_t o = 0;
    auto alloc = [&](size_t bytes) -> void* {
        o = (o + 255) & ~(size_t)255;
        void* p = ws + o;
        o += bytes;
        return p;
    };
    int* lhistT = (int*)alloc((size_t)NBKT * NBLK * sizeof(int));
    int* lbase = (int*)alloc((size_t)NBKT * NBLK * sizeof(int));
    int* btot = (int*)alloc((size_t)NBKT * sizeof(int));
    int* gregion = (int*)alloc(((size_t)NBKT + 1) * sizeof(int));
    unsigned int* pairs = (unsigned int*)alloc((size_t)E * sizeof(unsigned int));
    int* srcs = (int*)alloc(((size_t)E + (size_t)16 * N + 256) * sizeof(int));
    int* nh = (int*)alloc((size_t)GSUB * N * sizeof(int));
    int2* lc = (int2*)alloc((size_t)N * sizeof(int2));
    int* btot2 = (int*)alloc((size_t)NBLK2 * sizeof(int));
    int* bbase2 = (int*)alloc((size_t)NBLK2 * sizeof(int));
    int2* off2 = (int2*)alloc((size_t)N * sizeof(int2));
    float* dinv = (float*)alloc((size_t)N * sizeof(float));
    __half* u0 = (__half*)alloc((size_t)(N + 1) * 16 * sizeof(__half));
    __half* u1 = (__half*)alloc((size_t)(N + 1) * 16 * sizeof(__half));
    (void)ws_size;
    (void)n_in;
    (void)out_size;

    k_lhist<<<NBLK, 256, 0, stream>>>(edges, lhistT, E, NBLK);
    k_cscan<<<NBKT, 256, 0, stream>>>(lhistT, lbase, btot, NBLK);
    k_gscan<<<1, NBKT, 0, stream>>>(btot, gregion);
    k_scatter<<<NBLK, 256, 0, stream>>>(edges, gregion, lbase, pairs, E, NBLK);
    k_nhist<<<NUSED * GSUB, 256, 0, stream>>>(pairs, gregion, nh, N);
    k_nscan<<<NBLK2, 256, 0, stream>>>(nh, dinv, lc, btot2, N);
    k_prep<<<NBLK2, 256, 0, stream>>>(x, dinv, W, (__half2*)u0, (__half2*)u1, N);
    k_gscan2<<<1, 512, 0, stream>>>(btot2, bbase2, NBLK2);
    k_nfill<<<NBLK2, 256, 0, stream>>>(lc, bbase2, off2, srcs, N);
    k_nscatter<<<NUSED * GSUB, 256, 0, stream>>>(pairs, gregion, nh, off2, srcs, N);

    k_hop<0><<<2048, 256, 0, stream>>>((const uint2*)u0, srcs, off2, dinv, nullptr,
                                       (uint2*)u1, nullptr, N);
    k_hop<1><<<2048, 256, 0, stream>>>((const uint2*)u1, srcs, off2, dinv, b,
                                       nullptr, out, N);
}

// Round 15
// 140.984 us; speedup vs baseline: 5.3804x; 1.0822x over previous
//
#include <hip/hip_runtime.h>
#include <hip/hip_fp16.h>

#define NF 14
#define DIMOUT 16
#define BSH 9        // 512 nodes per bucket
#define NPBKT 512
#define NBKT 256     // bucket count (used: ceil(N/512) = 196)
#define C1 4096      // edges per block in bucket passes
#define GSUB 8       // subchunks per bucket in node-level passes

// int64 edge buffer <=> odd 32-bit words (high halves) all zero (ids < 2^31)
__device__ __forceinline__ bool detect64(const int* e32) {
    bool is64 = true;
#pragma unroll
    for (int i = 1; i < 64; i += 2) is64 &= (e32[i] == 0);
    return is64;
}

// ---- per-block bucket histogram (transposed write); 16B paired loads ----
__global__ __launch_bounds__(256) void k_lhist(const void* __restrict__ edges,
                                               int* __restrict__ lhistT, int E, int NBLK) {
    __shared__ int h[NBKT];
    const int t = threadIdx.x;
    h[t] = 0;
    __syncthreads();
    const int* e32 = (const int*)edges;
    const long long* e64 = (const long long*)edges;
    const bool is64 = detect64(e32);
    const int base = blockIdx.x * C1;
    const int cnt = min(C1, E - base);  // always even (E, C1 even)
    if (is64) {
        const longlong2* p2 = (const longlong2*)(e64 + (size_t)E + base);
        for (int j = 2 * t; j < cnt; j += 512) {
            longlong2 v = p2[j >> 1];
            atomicAdd(&h[((int)v.x) >> BSH], 1);
            atomicAdd(&h[((int)v.y) >> BSH], 1);
        }
    } else {
        const int2* p2 = (const int2*)(e32 + (size_t)E + base);
        for (int j = 2 * t; j < cnt; j += 512) {
            int2 v = p2[j >> 1];
            atomicAdd(&h[v.x >> BSH], 1);
            atomicAdd(&h[v.y >> BSH], 1);
        }
    }
    __syncthreads();
    lhistT[(size_t)t * NBLK + blockIdx.x] = h[t];
}

// ---- per-bucket scan over blocks ----
__global__ __launch_bounds__(256) void k_cscan(const int* __restrict__ lhistT,
                                               int* __restrict__ lbase,
                                               int* __restrict__ btot, int NBLK) {
    const int b = blockIdx.x;
    const int t = threadIdx.x;
    const int IPT = (NBLK + 255) / 256;
    int v[8];
    int s = 0;
    for (int k = 0; k < IPT; ++k) {
        int j = t * IPT + k;
        int x = (j < NBLK) ? lhistT[(size_t)b * NBLK + j] : 0;
        v[k] = x;
        s += x;
    }
    __shared__ int sm[256];
    sm[t] = s;
    __syncthreads();
    for (int d = 1; d < 256; d <<= 1) {
        int u = (t >= d) ? sm[t - d] : 0;
        __syncthreads();
        sm[t] += u;
        __syncthreads();
    }
    int run = sm[t] - s;
    for (int k = 0; k < IPT; ++k) {
        int j = t * IPT + k;
        if (j < NBLK) {
            lbase[(size_t)b * NBLK + j] = run;
            run += v[k];
        }
    }
    if (t == 255) btot[b] = sm[255];
}

// ---- scan bucket totals -> regions ----
__global__ __launch_bounds__(NBKT) void k_gscan(const int* __restrict__ btot,
                                                int* __restrict__ gregion) {
    __shared__ int sm[NBKT];
    int t = threadIdx.x;
    int v = btot[t];
    sm[t] = v;
    __syncthreads();
    for (int d = 1; d < NBKT; d <<= 1) {
        int u = (t >= d) ? sm[t - d] : 0;
        __syncthreads();
        sm[t] += u;
        __syncthreads();
    }
    gregion[t] = sm[t] - v;
    if (t == NBKT - 1) gregion[NBKT] = sm[t];
}

// ---- bucket scatter: block-local LDS counting sort, runs at exact bases ----
// packed entry: (dst & 511) << 17 | src ; 16B paired edge loads
__global__ __launch_bounds__(256) void k_scatter(const void* __restrict__ edges,
                                                 const int* __restrict__ gregion,
                                                 const int* __restrict__ lbase,
                                                 unsigned int* __restrict__ pairs,
                                                 int E, int NBLK) {
    __shared__ unsigned int raw[C1];
    __shared__ unsigned int srt[C1];
    __shared__ unsigned short bkt[C1];
    __shared__ unsigned char sbk[C1];
    __shared__ int hist[NBKT], scn[NBKT], gb[NBKT], cur[NBKT];
    const int* e32 = (const int*)edges;
    const long long* e64 = (const long long*)edges;
    const bool is64 = detect64(e32);
    const int t = threadIdx.x;
    const int base = blockIdx.x * C1;
    const int cnt = min(C1, E - base);  // always even
    hist[t] = 0;
    cur[t] = 0;
    __syncthreads();
    for (int j = 2 * t; j < cnt; j += 512) {
        int s0, s1, d0, d1;
        if (is64) {
            longlong2 vs = *(const longlong2*)(e64 + (size_t)base + j);
            longlong2 vd = *(const longlong2*)(e64 + (size_t)E + base + j);
            s0 = (int)vs.x;
            s1 = (int)vs.y;
            d0 = (int)vd.x;
            d1 = (int)vd.y;
        } else {
            int2 vs = *(const int2*)(e32 + (size_t)base + j);
            int2 vd = *(const int2*)(e32 + (size_t)E + base + j);
            s0 = vs.x;
            s1 = vs.y;
            d0 = vd.x;
            d1 = vd.y;
        }
        int b0 = d0 >> BSH, b1 = d1 >> BSH;
        raw[j] = (unsigned int)s0 | ((unsigned int)(d0 & (NPBKT - 1)) << 17);
        raw[j + 1] = (unsigned int)s1 | ((unsigned int)(d1 & (NPBKT - 1)) << 17);
        bkt[j] = (unsigned short)b0;
        bkt[j + 1] = (unsigned short)b1;
        atomicAdd(&hist[b0], 1);
        atomicAdd(&hist[b1], 1);
    }
    __syncthreads();
    int v = hist[t];
    scn[t] = v;
    __syncthreads();
    for (int d = 1; d < NBKT; d <<= 1) {
        int u = (t >= d) ? scn[t - d] : 0;
        __syncthreads();
        scn[t] += u;
        __syncthreads();
    }
    int ex = scn[t] - v;
    gb[t] = gregion[t] + lbase[(size_t)t * NBLK + blockIdx.x];
    __syncthreads();
    scn[t] = ex;
    __syncthreads();
    for (int j = t; j < cnt; j += 256) {
        int b = bkt[j];
        int r = atomicAdd(&cur[b], 1);
        int pos = scn[b] + r;
        srt[pos] = raw[j];
        sbk[pos] = (unsigned char)b;
    }
    __syncthreads();
    for (int j = t; j < cnt; j += 256) {
        int b = sbk[j];
        pairs[gb[b] + (j - scn[b])] = srt[j];
    }
}

// ---- node-level histogram per (bucket, subchunk); g-major layout ----
__global__ __launch_bounds__(256) void k_nhist(const unsigned int* __restrict__ pairs,
                                               const int* __restrict__ gregion,
                                               int* __restrict__ nh, int N) {
    const int b = blockIdx.x >> 3;
    const int g = blockIdx.x & 7;
    const int e0 = gregion[b], e1 = gregion[b + 1];
    const int L = e1 - e0;
    const int sb = e0 + ((L * g) >> 3);
    const int se = e0 + ((L * (g + 1)) >> 3);
    __shared__ int h[NPBKT];
    const int t = threadIdx.x;
    h[t] = 0;
    h[t + 256] = 0;
    __syncthreads();
    for (int e = sb + t; e < se; e += 256) atomicAdd(&h[pairs[e] >> 17], 1);
    __syncthreads();
    const int nbase = b << BSH;
    for (int l = t; l < NPBKT; l += 256) {
        int n = nbase + l;
        if (n < N) nh[(size_t)g * N + n] = h[l];
    }
}

// ---- per-node scan over subchunks + block scan of padded degrees ----
// padded slots = round_up(deg + 1, 8): self-loop in-list, pad to 8
__global__ __launch_bounds__(256) void k_nscan(int* __restrict__ nh,
                                               float* __restrict__ dinv,
                                               int2* __restrict__ lc,
                                               int* __restrict__ btot2, int N) {
    const int t = threadIdx.x;
    const int n = blockIdx.x * 256 + t;
    int c = 0, p = 0;
    if (n < N) {
        int v[GSUB];
        int ex = 0;
#pragma unroll
        for (int g = 0; g < GSUB; ++g) v[g] = nh[(size_t)g * N + n];
#pragma unroll
        for (int g = 0; g < GSUB; ++g) {
            int vv = v[g];
            nh[(size_t)g * N + n] = ex;  // counts -> exclusive bases (in place)
            ex += vv;
        }
        c = ex;
        p = (c + 8) & ~7;  // self-loop + pad to multiple of 8
        dinv[n] = rsqrtf((float)(c + 1));
    }
    __shared__ int sm[256];
    sm[t] = p;
    __syncthreads();
    for (int d = 1; d < 256; d <<= 1) {
        int u = (t >= d) ? sm[t - d] : 0;
        __syncthreads();
        sm[t] += u;
        __syncthreads();
    }
    if (n < N) lc[n] = make_int2(sm[t] - p, c);  // (local offset, degree)
    if (t == 255) btot2[blockIdx.x] = sm[255];
}

// ---- scan per-block padded totals ----
__global__ __launch_bounds__(512) void k_gscan2(const int* __restrict__ btot2,
                                                int* __restrict__ bbase2, int nb) {
    __shared__ int sm[512];
    int t = threadIdx.x;
    int v = (t < nb) ? btot2[t] : 0;
    sm[t] = v;
    __syncthreads();
    for (int d = 1; d < 512; d <<= 1) {
        int u = (t >= d) ? sm[t - d] : 0;
        __syncthreads();
        sm[t] += u;
        __syncthreads();
    }
    if (t < nb) bbase2[t] = sm[t] - v;
}

// ---- node-level scatter (+ fused offset finalize / self-loop / pads) ----
// off computed directly from bbase2 + lc; g==0 block also writes off2, the
// self-loop entry (slot 0) and the sentinel pads for its 512 nodes.
__global__ __launch_bounds__(256) void k_nscatter(const unsigned int* __restrict__ pairs,
                                                  const int* __restrict__ gregion,
                                                  const int* __restrict__ nh,
                                                  const int2* __restrict__ lc,
                                                  const int* __restrict__ bbase2,
                                                  int2* __restrict__ off2,
                                                  int* __restrict__ srcs, int N) {
    const int b = blockIdx.x >> 3;
    const int g = blockIdx.x & 7;
    const int e0 = gregion[b], e1 = gregion[b + 1];
    const int L = e1 - e0;
    const int sb = e0 + ((L * g) >> 3);
    const int se = e0 + ((L * (g + 1)) >> 3);
    __shared__ int cur[NPBKT];
    const int t = threadIdx.x;
    const int nbase = b << BSH;
    for (int l = t; l < NPBKT; l += 256) {
        int n = nbase + l;
        if (n < N) {
            int2 lcv = lc[n];
            int off = bbase2[n >> 8] + lcv.x;
            cur[l] = off + 1 + nh[(size_t)g * N + n];
            if (g == 0) {
                int c = lcv.y;
                int p = (c + 8) & ~7;
                off2[n] = make_int2(off, off + p);
                srcs[off] = n;  // self loop at slot 0
                for (int k = c + 1; k < p; ++k) srcs[off + k] = N;  // sentinel pad
            }
        }
    }
    __syncthreads();
    for (int e = sb + t; e < se; e += 256) {
        unsigned int pr = pairs[e];
        int l = pr >> 17;
        int r = atomicAdd(&cur[l], 1);  // LDS only
        srcs[r] = (int)(pr & 0x1FFFFu);
    }
}

// ---- prep: u0[n] = fp16( dinv[n] * (x[n] @ W^T) ); zero sentinel rows ----
__global__ __launch_bounds__(256) void k_prep(const float* __restrict__ x,
                                              const float* __restrict__ dinv,
                                              const float* __restrict__ Wg,
                                              __half2* __restrict__ u0,
                                              __half2* __restrict__ u1, int N) {
    __shared__ float Wl[DIMOUT * NF];
    int t = threadIdx.x;
    if (t < DIMOUT * NF) Wl[t] = Wg[t];
    __syncthreads();
    if (blockIdx.x == 0 && t < 8) {  // zero sentinel rows (src == N)
        u0[(size_t)N * 8 + t] = __floats2half2_rn(0.f, 0.f);
        u1[(size_t)N * 8 + t] = __floats2half2_rn(0.f, 0.f);
    }
    int n = blockIdx.x * 256 + t;
    if (n >= N) return;
    float xr[NF];
    const float2* xr2 = (const float2*)(x + (size_t)n * NF);
#pragma unroll
    for (int k = 0; k < 7; ++k) {
        float2 v = xr2[k];
        xr[2 * k] = v.x;
        xr[2 * k + 1] = v.y;
    }
    float dn = dinv[n];
#pragma unroll
    for (int q = 0; q < 8; ++q) {
        float r0 = 0.f, r1 = 0.f;
#pragma unroll
        for (int f = 0; f < NF; ++f) {
            r0 += xr[f] * Wl[(2 * q) * NF + f];
            r1 += xr[f] * Wl[(2 * q + 1) * NF + f];
        }
        u0[(size_t)n * 8 + q] = __floats2half2_rn(dn * r0, dn * r1);
    }
}

// ---- hop: grid-stride, 2 nodes per wave (half-wave each), 8-way
// edge-parallel, 8B lanes, pad-8 lists. Reduce over ep = 3 shfl rounds. ----
template <int FINAL>
__global__ __launch_bounds__(256) void k_hop(const uint2* __restrict__ u8,
                                             const int* __restrict__ srcs,
                                             const int2* __restrict__ off2,
                                             const float* __restrict__ dinv,
                                             const float* __restrict__ bias,
                                             uint2* __restrict__ outh,
                                             float* __restrict__ outf, int N) {
    const int lane = threadIdx.x & 63;
    const int fp = lane & 3;          // 8B quarter of 32B row
    const int ep = (lane >> 2) & 7;   // 8 edge subgroups per half-wave
    const int half = lane >> 5;       // which node this half-wave owns
    const int wid = threadIdx.x >> 6;
    float4 breg = make_float4(0.f, 0.f, 0.f, 0.f);
    if (FINAL) breg = *(const float4*)(bias + 4 * fp);
    const int stride = gridDim.x * 8;  // 4 waves x 2 nodes per block
    for (int n0 = blockIdx.x * 8 + wid * 2; n0 < N; n0 += stride) {
        const int n = n0 + half;
        const bool act = (n < N);
        int2 oo = act ? off2[n] : make_int2(0, 0);
        float ax = 0.f, ay = 0.f, az = 0.f, aw = 0.f;
        int e = oo.x + ep;
        for (; e + 8 < oo.y; e += 16) {  // 2-deep: 16 slots per half-wave iter
            int s0 = srcs[e];
            int s1 = srcs[e + 8];
            uint2 q0 = u8[(size_t)s0 * 4 + fp];
            uint2 q1 = u8[(size_t)s1 * 4 + fp];
            float2 a0 = __half22float2(*(__half2*)&q0.x);
            float2 b0 = __half22float2(*(__half2*)&q0.y);
            float2 a1 = __half22float2(*(__half2*)&q1.x);
            float2 b1 = __half22float2(*(__half2*)&q1.y);
            ax += a0.x + a1.x;
            ay += a0.y + a1.y;
            az += b0.x + b1.x;
            aw += b0.y + b1.y;
        }
        if (e < oo.y) {  // at most one leftover 8-chunk
            int s0 = srcs[e];
            uint2 q0 = u8[(size_t)s0 * 4 + fp];
            float2 a0 = __half22float2(*(__half2*)&q0.x);
            float2 b0 = __half22float2(*(__half2*)&q0.y);
            ax += a0.x;
            ay += a0.y;
            az += b0.x;
            aw += b0.y;
        }
#pragma unroll
        for (int d = 4; d <= 16; d <<= 1) {  // reduce over ep, stays in-half
            ax += __shfl_xor(ax, d);
            ay += __shfl_xor(ay, d);
            az += __shfl_xor(az, d);
            aw += __shfl_xor(aw, d);
        }
        if (ep == 0 && act) {
            float dn = dinv[n];
            if (!FINAL) {
                float s = dn * dn;
                __half2 h0 = __floats2half2_rn(s * ax, s * ay);
                __half2 h1 = __floats2half2_rn(s * az, s * aw);
                uint2 q;
                q.x = *(unsigned*)&h0;
                q.y = *(unsigned*)&h1;
                outh[(size_t)n * 4 + fp] = q;
            } else {
                float4 o;
                o.x = dn * ax + breg.x;
                o.y = dn * ay + breg.y;
                o.z = dn * az + breg.z;
                o.w = dn * aw + breg.w;
                *(float4*)(outf + (size_t)n * DIMOUT + 4 * fp) = o;
            }
        }
    }
}

extern "C" void kernel_launch(void* const* d_in, const int* in_sizes, int n_in,
                              void* d_out, int out_size, void* d_ws, size_t ws_size,
                              hipStream_t stream) {
    const float* x = (const float*)d_in[0];
    const void* edges = d_in[1];
    const float* W = (const float*)d_in[2];
    const float* b = (const float*)d_in[3];
    float* out = (float*)d_out;

    const int N = in_sizes[0] / NF;  // 100000
    const int E = in_sizes[1] / 2;   // 3200000
    const int NBLK = (E + C1 - 1) / C1;
    const int NUSED = (N + NPBKT - 1) >> BSH;
    const int NBLK2 = (N + 255) / 256;

    char* ws = (char*)d_ws;
    size_t o = 0;
    auto alloc = [&](size_t bytes) -> void* {
        o = (o + 255) & ~(size_t)255;
        void* p = ws + o;
        o += bytes;
        return p;
    };
    int* lhistT = (int*)alloc((size_t)NBKT * NBLK * sizeof(int));
    int* lbase = (int*)alloc((size_t)NBKT * NBLK * sizeof(int));
    int* btot = (int*)alloc((size_t)NBKT * sizeof(int));
    int* gregion = (int*)alloc(((size_t)NBKT + 1) * sizeof(int));
    unsigned int* pairs = (unsigned int*)alloc((size_t)E * sizeof(unsigned int));
    int* srcs = (int*)alloc(((size_t)E + (size_t)8 * N + 256) * sizeof(int));
    int* nh = (int*)alloc((size_t)GSUB * N * sizeof(int));
    int2* lc = (int2*)alloc((size_t)N * sizeof(int2));
    int* btot2 = (int*)alloc((size_t)NBLK2 * sizeof(int));
    int* bbase2 = (int*)alloc((size_t)NBLK2 * sizeof(int));
    int2* off2 = (int2*)alloc((size_t)N * sizeof(int2));
    float* dinv = (float*)alloc((size_t)N * sizeof(float));
    __half* u0 = (__half*)alloc((size_t)(N + 1) * 16 * sizeof(__half));
    __half* u1 = (__half*)alloc((size_t)(N + 1) * 16 * sizeof(__half));
    (void)ws_size;
    (void)n_in;
    (void)out_size;

    k_lhist<<<NBLK, 256, 0, stream>>>(edges, lhistT, E, NBLK);
    k_cscan<<<NBKT, 256, 0, stream>>>(lhistT, lbase, btot, NBLK);
    k_gscan<<<1, NBKT, 0, stream>>>(btot, gregion);
    k_scatter<<<NBLK, 256, 0, stream>>>(edges, gregion, lbase, pairs, E, NBLK);
    k_nhist<<<NUSED * GSUB, 256, 0, stream>>>(pairs, gregion, nh, N);
    k_nscan<<<NBLK2, 256, 0, stream>>>(nh, dinv, lc, btot2, N);
    k_prep<<<NBLK2, 256, 0, stream>>>(x, dinv, W, (__half2*)u0, (__half2*)u1, N);
    k_gscan2<<<1, 512, 0, stream>>>(btot2, bbase2, NBLK2);
    k_nscatter<<<NUSED * GSUB, 256, 0, stream>>>(pairs, gregion, nh, lc, bbase2,
                                                 off2, srcs, N);

    k_hop<0><<<2048, 256, 0, stream>>>((const uint2*)u0, srcs, off2, dinv, nullptr,
                                       (uint2*)u1, nullptr, N);
    k_hop<1><<<2048, 256, 0, stream>>>((const uint2*)u1, srcs, off2, dinv, b,
                                       nullptr, out, N);
}

// Round 16
// 121.339 us; speedup vs baseline: 6.2516x; 1.1619x over previous
//
#include <hip/hip_runtime.h>
#include <hip/hip_fp16.h>

#define NF 14
#define DIMOUT 16
#define BSH 9        // 512 nodes per bucket
#define NPBKT 512
#define NBKT 256     // bucket count (used: ceil(N/512) = 196)
#define C1 4096      // edges per block in bucket passes
#define HNODES 256   // nodes per half-bucket
#define SCAP 14336   // LDS staging capacity (entries) per half-bucket

// int64 edge buffer <=> odd 32-bit words (high halves) all zero (ids < 2^31)
__device__ __forceinline__ bool detect64(const int* e32) {
    bool is64 = true;
#pragma unroll
    for (int i = 1; i < 64; i += 2) is64 &= (e32[i] == 0);
    return is64;
}

// ---- per-block bucket histogram (transposed write); 16B paired loads ----
__global__ __launch_bounds__(256) void k_lhist(const void* __restrict__ edges,
                                               int* __restrict__ lhistT, int E, int NBLK) {
    __shared__ int h[NBKT];
    const int t = threadIdx.x;
    h[t] = 0;
    __syncthreads();
    const int* e32 = (const int*)edges;
    const long long* e64 = (const long long*)edges;
    const bool is64 = detect64(e32);
    const int base = blockIdx.x * C1;
    const int cnt = min(C1, E - base);  // always even (E, C1 even)
    if (is64) {
        const longlong2* p2 = (const longlong2*)(e64 + (size_t)E + base);
        for (int j = 2 * t; j < cnt; j += 512) {
            longlong2 v = p2[j >> 1];
            atomicAdd(&h[((int)v.x) >> BSH], 1);
            atomicAdd(&h[((int)v.y) >> BSH], 1);
        }
    } else {
        const int2* p2 = (const int2*)(e32 + (size_t)E + base);
        for (int j = 2 * t; j < cnt; j += 512) {
            int2 v = p2[j >> 1];
            atomicAdd(&h[v.x >> BSH], 1);
            atomicAdd(&h[v.y >> BSH], 1);
        }
    }
    __syncthreads();
    lhistT[(size_t)t * NBLK + blockIdx.x] = h[t];
}

// ---- per-bucket scan over blocks ----
__global__ __launch_bounds__(256) void k_cscan(const int* __restrict__ lhistT,
                                               int* __restrict__ lbase,
                                               int* __restrict__ btot, int NBLK) {
    const int b = blockIdx.x;
    const int t = threadIdx.x;
    const int IPT = (NBLK + 255) / 256;
    int v[8];
    int s = 0;
    for (int k = 0; k < IPT; ++k) {
        int j = t * IPT + k;
        int x = (j < NBLK) ? lhistT[(size_t)b * NBLK + j] : 0;
        v[k] = x;
        s += x;
    }
    __shared__ int sm[256];
    sm[t] = s;
    __syncthreads();
    for (int d = 1; d < 256; d <<= 1) {
        int u = (t >= d) ? sm[t - d] : 0;
        __syncthreads();
        sm[t] += u;
        __syncthreads();
    }
    int run = sm[t] - s;
    for (int k = 0; k < IPT; ++k) {
        int j = t * IPT + k;
        if (j < NBLK) {
            lbase[(size_t)b * NBLK + j] = run;
            run += v[k];
        }
    }
    if (t == 255) btot[b] = sm[255];
}

// ---- scan bucket totals -> regions ----
__global__ __launch_bounds__(NBKT) void k_gscan(const int* __restrict__ btot,
                                                int* __restrict__ gregion) {
    __shared__ int sm[NBKT];
    int t = threadIdx.x;
    int v = btot[t];
    sm[t] = v;
    __syncthreads();
    for (int d = 1; d < NBKT; d <<= 1) {
        int u = (t >= d) ? sm[t - d] : 0;
        __syncthreads();
        sm[t] += u;
        __syncthreads();
    }
    gregion[t] = sm[t] - v;
    if (t == NBKT - 1) gregion[NBKT] = sm[t];
}

// ---- bucket scatter: block-local LDS counting sort, runs at exact bases ----
// packed entry: (dst & 511) << 17 | src ; 16B paired edge loads
__global__ __launch_bounds__(256) void k_scatter(const void* __restrict__ edges,
                                                 const int* __restrict__ gregion,
                                                 const int* __restrict__ lbase,
                                                 unsigned int* __restrict__ pairs,
                                                 int E, int NBLK) {
    __shared__ unsigned int raw[C1];
    __shared__ unsigned int srt[C1];
    __shared__ unsigned short bkt[C1];
    __shared__ unsigned char sbk[C1];
    __shared__ int hist[NBKT], scn[NBKT], gb[NBKT], cur[NBKT];
    const int* e32 = (const int*)edges;
    const long long* e64 = (const long long*)edges;
    const bool is64 = detect64(e32);
    const int t = threadIdx.x;
    const int base = blockIdx.x * C1;
    const int cnt = min(C1, E - base);  // always even
    hist[t] = 0;
    cur[t] = 0;
    __syncthreads();
    for (int j = 2 * t; j < cnt; j += 512) {
        int s0, s1, d0, d1;
        if (is64) {
            longlong2 vs = *(const longlong2*)(e64 + (size_t)base + j);
            longlong2 vd = *(const longlong2*)(e64 + (size_t)E + base + j);
            s0 = (int)vs.x;
            s1 = (int)vs.y;
            d0 = (int)vd.x;
            d1 = (int)vd.y;
        } else {
            int2 vs = *(const int2*)(e32 + (size_t)base + j);
            int2 vd = *(const int2*)(e32 + (size_t)E + base + j);
            s0 = vs.x;
            s1 = vs.y;
            d0 = vd.x;
            d1 = vd.y;
        }
        int b0 = d0 >> BSH, b1 = d1 >> BSH;
        raw[j] = (unsigned int)s0 | ((unsigned int)(d0 & (NPBKT - 1)) << 17);
        raw[j + 1] = (unsigned int)s1 | ((unsigned int)(d1 & (NPBKT - 1)) << 17);
        bkt[j] = (unsigned short)b0;
        bkt[j + 1] = (unsigned short)b1;
        atomicAdd(&hist[b0], 1);
        atomicAdd(&hist[b1], 1);
    }
    __syncthreads();
    int v = hist[t];
    scn[t] = v;
    __syncthreads();
    for (int d = 1; d < NBKT; d <<= 1) {
        int u = (t >= d) ? scn[t - d] : 0;
        __syncthreads();
        scn[t] += u;
        __syncthreads();
    }
    int ex = scn[t] - v;
    gb[t] = gregion[t] + lbase[(size_t)t * NBLK + blockIdx.x];
    __syncthreads();
    scn[t] = ex;
    __syncthreads();
    for (int j = t; j < cnt; j += 256) {
        int b = bkt[j];
        int r = atomicAdd(&cur[b], 1);
        int pos = scn[b] + r;
        srt[pos] = raw[j];
        sbk[pos] = (unsigned char)b;
    }
    __syncthreads();
    for (int j = t; j < cnt; j += 256) {
        int b = sbk[j];
        pairs[gb[b] + (j - scn[b])] = srt[j];
    }
}

// ---- pass A: per half-bucket degree count -> dinv, local offsets, padded total ----
__global__ __launch_bounds__(512) void k_hcount(const unsigned int* __restrict__ pairs,
                                                const int* __restrict__ gregion,
                                                float* __restrict__ dinv,
                                                int2* __restrict__ lc,
                                                int* __restrict__ htot, int N) {
    const int bh = blockIdx.x;
    const int b = bh >> 1, h = bh & 1;
    const int e0 = gregion[b], e1 = gregion[b + 1];
    __shared__ int cnt[HNODES];
    __shared__ int sm[HNODES];
    const int t = threadIdx.x;
    if (t < HNODES) cnt[t] = 0;
    __syncthreads();
    for (int e = e0 + t; e < e1; e += 512) {
        int dl = (int)(pairs[e] >> 17);
        if ((dl >> 8) == h) atomicAdd(&cnt[dl & (HNODES - 1)], 1);
    }
    __syncthreads();
    const int nbase = (b << BSH) + h * HNODES;
    int c = 0, p = 0;
    if (t < HNODES) {
        c = cnt[t];
        if (nbase + t < N) p = (c + 8) & ~7;  // self-loop + pad to 8
    }
    if (t < HNODES) sm[t] = p;
    __syncthreads();
    for (int d = 1; d < HNODES; d <<= 1) {
        int u = (t >= d && t < HNODES) ? sm[t - d] : 0;
        __syncthreads();
        if (t < HNODES) sm[t] += u;
        __syncthreads();
    }
    if (t < HNODES && nbase + t < N) {
        lc[nbase + t] = make_int2(sm[t] - p, c);  // (local offset, degree)
        dinv[nbase + t] = rsqrtf((float)(c + 1));
    }
    if (t == 0) htot[bh] = sm[HNODES - 1];
}

// ---- scan per-half-bucket padded totals ----
__global__ __launch_bounds__(512) void k_gscan2(const int* __restrict__ htot,
                                                int* __restrict__ hbase, int nb) {
    __shared__ int sm[512];
    int t = threadIdx.x;
    int v = (t < nb) ? htot[t] : 0;
    sm[t] = v;
    __syncthreads();
    for (int d = 1; d < 512; d <<= 1) {
        int u = (t >= d) ? sm[t - d] : 0;
        __syncthreads();
        sm[t] += u;
        __syncthreads();
    }
    if (t < nb) hbase[t] = sm[t] - v;
}

// ---- pass B: stage half-bucket srcs in LDS, burst-write coalesced ----
__global__ __launch_bounds__(512) void k_hplace(const unsigned int* __restrict__ pairs,
                                                const int* __restrict__ gregion,
                                                const int2* __restrict__ lc,
                                                const int* __restrict__ hbase,
                                                const int* __restrict__ htot,
                                                int2* __restrict__ off2,
                                                int* __restrict__ srcs, int N) {
    const int bh = blockIdx.x;
    const int b = bh >> 1, h = bh & 1;
    const int e0 = gregion[b], e1 = gregion[b + 1];
    __shared__ int cur[HNODES];
    __shared__ unsigned staged[SCAP];
    const int t = threadIdx.x;
    const int nbase = (b << BSH) + h * HNODES;
    const int gb = hbase[bh];
    const int span = htot[bh];
    const bool fits = (span <= SCAP);
    if (t < HNODES) {
        int n = nbase + t;
        if (n < N) {
            int2 l = lc[n];
            int c = l.y;
            int p = (c + 8) & ~7;
            off2[n] = make_int2(gb + l.x, gb + l.x + p);
            if (fits) {
                cur[t] = l.x + 1;
                staged[l.x] = (unsigned)n;  // self loop at slot 0
                for (int k = c + 1; k < p; ++k) staged[l.x + k] = (unsigned)N;
            } else {  // fallback: direct global writes
                cur[t] = gb + l.x + 1;
                srcs[gb + l.x] = n;
                for (int k = c + 1; k < p; ++k) srcs[gb + l.x + k] = N;
            }
        } else {
            cur[t] = 0;
        }
    }
    __syncthreads();
    if (fits) {
        for (int e = e0 + t; e < e1; e += 512) {
            unsigned pr = pairs[e];
            int dl = (int)(pr >> 17);
            if ((dl >> 8) == h) {
                int r = atomicAdd(&cur[dl & (HNODES - 1)], 1);  // LDS only
                staged[r] = pr & 0x1FFFFu;
            }
        }
        __syncthreads();
        for (int i = t; i < span; i += 512) srcs[gb + i] = (int)staged[i];
    } else {
        for (int e = e0 + t; e < e1; e += 512) {
            unsigned pr = pairs[e];
            int dl = (int)(pr >> 17);
            if ((dl >> 8) == h) {
                int r = atomicAdd(&cur[dl & (HNODES - 1)], 1);
                srcs[r] = (int)(pr & 0x1FFFFu);
            }
        }
    }
}

// ---- prep: u0[n] = fp16( dinv[n] * (x[n] @ W^T) ); zero sentinel rows ----
__global__ __launch_bounds__(256) void k_prep(const float* __restrict__ x,
                                              const float* __restrict__ dinv,
                                              const float* __restrict__ Wg,
                                              __half2* __restrict__ u0,
                                              __half2* __restrict__ u1, int N) {
    __shared__ float Wl[DIMOUT * NF];
    int t = threadIdx.x;
    if (t < DIMOUT * NF) Wl[t] = Wg[t];
    __syncthreads();
    if (blockIdx.x == 0 && t < 8) {  // zero sentinel rows (src == N)
        u0[(size_t)N * 8 + t] = __floats2half2_rn(0.f, 0.f);
        u1[(size_t)N * 8 + t] = __floats2half2_rn(0.f, 0.f);
    }
    int n = blockIdx.x * 256 + t;
    if (n >= N) return;
    float xr[NF];
    const float2* xr2 = (const float2*)(x + (size_t)n * NF);
#pragma unroll
    for (int k = 0; k < 7; ++k) {
        float2 v = xr2[k];
        xr[2 * k] = v.x;
        xr[2 * k + 1] = v.y;
    }
    float dn = dinv[n];
#pragma unroll
    for (int q = 0; q < 8; ++q) {
        float r0 = 0.f, r1 = 0.f;
#pragma unroll
        for (int f = 0; f < NF; ++f) {
            r0 += xr[f] * Wl[(2 * q) * NF + f];
            r1 += xr[f] * Wl[(2 * q + 1) * NF + f];
        }
        u0[(size_t)n * 8 + q] = __floats2half2_rn(dn * r0, dn * r1);
    }
}

// ---- hop: grid-stride, 2 nodes per wave (half-wave each), 8-way
// edge-parallel, 8B lanes, pad-8 lists. Reduce over ep = 3 shfl rounds. ----
template <int FINAL>
__global__ __launch_bounds__(256) void k_hop(const uint2* __restrict__ u8,
                                             const int* __restrict__ srcs,
                                             const int2* __restrict__ off2,
                                             const float* __restrict__ dinv,
                                             const float* __restrict__ bias,
                                             uint2* __restrict__ outh,
                                             float* __restrict__ outf, int N) {
    const int lane = threadIdx.x & 63;
    const int fp = lane & 3;          // 8B quarter of 32B row
    const int ep = (lane >> 2) & 7;   // 8 edge subgroups per half-wave
    const int half = lane >> 5;       // which node this half-wave owns
    const int wid = threadIdx.x >> 6;
    float4 breg = make_float4(0.f, 0.f, 0.f, 0.f);
    if (FINAL) breg = *(const float4*)(bias + 4 * fp);
    const int stride = gridDim.x * 8;  // 4 waves x 2 nodes per block
    for (int n0 = blockIdx.x * 8 + wid * 2; n0 < N; n0 += stride) {
        const int n = n0 + half;
        const bool act = (n < N);
        int2 oo = act ? off2[n] : make_int2(0, 0);
        float ax = 0.f, ay = 0.f, az = 0.f, aw = 0.f;
        int e = oo.x + ep;
        for (; e + 8 < oo.y; e += 16) {  // 2-deep: 16 slots per half-wave iter
            int s0 = srcs[e];
            int s1 = srcs[e + 8];
            uint2 q0 = u8[(size_t)s0 * 4 + fp];
            uint2 q1 = u8[(size_t)s1 * 4 + fp];
            float2 a0 = __half22float2(*(__half2*)&q0.x);
            float2 b0 = __half22float2(*(__half2*)&q0.y);
            float2 a1 = __half22float2(*(__half2*)&q1.x);
            float2 b1 = __half22float2(*(__half2*)&q1.y);
            ax += a0.x + a1.x;
            ay += a0.y + a1.y;
            az += b0.x + b1.x;
            aw += b0.y + b1.y;
        }
        if (e < oo.y) {  // at most one leftover 8-chunk
            int s0 = srcs[e];
            uint2 q0 = u8[(size_t)s0 * 4 + fp];
            float2 a0 = __half22float2(*(__half2*)&q0.x);
            float2 b0 = __half22float2(*(__half2*)&q0.y);
            ax += a0.x;
            ay += a0.y;
            az += b0.x;
            aw += b0.y;
        }
#pragma unroll
        for (int d = 4; d <= 16; d <<= 1) {  // reduce over ep, stays in-half
            ax += __shfl_xor(ax, d);
            ay += __shfl_xor(ay, d);
            az += __shfl_xor(az, d);
            aw += __shfl_xor(aw, d);
        }
        if (ep == 0 && act) {
            float dn = dinv[n];
            if (!FINAL) {
                float s = dn * dn;
                __half2 h0 = __floats2half2_rn(s * ax, s * ay);
                __half2 h1 = __floats2half2_rn(s * az, s * aw);
                uint2 q;
                q.x = *(unsigned*)&h0;
                q.y = *(unsigned*)&h1;
                outh[(size_t)n * 4 + fp] = q;
            } else {
                float4 o;
                o.x = dn * ax + breg.x;
                o.y = dn * ay + breg.y;
                o.z = dn * az + breg.z;
                o.w = dn * aw + breg.w;
                *(float4*)(outf + (size_t)n * DIMOUT + 4 * fp) = o;
            }
        }
    }
}

extern "C" void kernel_launch(void* const* d_in, const int* in_sizes, int n_in,
                              void* d_out, int out_size, void* d_ws, size_t ws_size,
                              hipStream_t stream) {
    const float* x = (const float*)d_in[0];
    const void* edges = d_in[1];
    const float* W = (const float*)d_in[2];
    const float* b = (const float*)d_in[3];
    float* out = (float*)d_out;

    const int N = in_sizes[0] / NF;  // 100000
    const int E = in_sizes[1] / 2;   // 3200000
    const int NBLK = (E + C1 - 1) / C1;
    const int NUSED = (N + NPBKT - 1) >> BSH;
    const int NBH = NUSED * 2;  // half-buckets

    char* ws = (char*)d_ws;
    size_t o = 0;
    auto alloc = [&](size_t bytes) -> void* {
        o = (o + 255) & ~(size_t)255;
        void* p = ws + o;
        o += bytes;
        return p;
    };
    int* lhistT = (int*)alloc((size_t)NBKT * NBLK * sizeof(int));
    int* lbase = (int*)alloc((size_t)NBKT * NBLK * sizeof(int));
    int* btot = (int*)alloc((size_t)NBKT * sizeof(int));
    int* gregion = (int*)alloc(((size_t)NBKT + 1) * sizeof(int));
    unsigned int* pairs = (unsigned int*)alloc((size_t)E * sizeof(unsigned int));
    int* srcs = (int*)alloc(((size_t)E + (size_t)8 * N + 256) * sizeof(int));
    int2* lc = (int2*)alloc((size_t)N * sizeof(int2));
    int* htot = (int*)alloc((size_t)NBH * sizeof(int));
    int* hbase = (int*)alloc((size_t)NBH * sizeof(int));
    int2* off2 = (int2*)alloc((size_t)N * sizeof(int2));
    float* dinv = (float*)alloc((size_t)N * sizeof(float));
    __half* u0 = (__half*)alloc((size_t)(N + 1) * 16 * sizeof(__half));
    __half* u1 = (__half*)alloc((size_t)(N + 1) * 16 * sizeof(__half));
    (void)ws_size;
    (void)n_in;
    (void)out_size;

    k_lhist<<<NBLK, 256, 0, stream>>>(edges, lhistT, E, NBLK);
    k_cscan<<<NBKT, 256, 0, stream>>>(lhistT, lbase, btot, NBLK);
    k_gscan<<<1, NBKT, 0, stream>>>(btot, gregion);
    k_scatter<<<NBLK, 256, 0, stream>>>(edges, gregion, lbase, pairs, E, NBLK);
    k_hcount<<<NBH, 512, 0, stream>>>(pairs, gregion, dinv, lc, htot, N);
    k_gscan2<<<1, 512, 0, stream>>>(htot, hbase, NBH);
    k_prep<<<(N + 255) / 256, 256, 0, stream>>>(x, dinv, W, (__half2*)u0,
                                                (__half2*)u1, N);
    k_hplace<<<NBH, 512, 0, stream>>>(pairs, gregion, lc, hbase, htot, off2, srcs, N);

    k_hop<0><<<2048, 256, 0, stream>>>((const uint2*)u0, srcs, off2, dinv, nullptr,
                                       (uint2*)u1, nullptr, N);
    k_hop<1><<<2048, 256, 0, stream>>>((const uint2*)u1, srcs, off2, dinv, b,
                                       nullptr, out, N);
}

// Round 17
// 116.932 us; speedup vs baseline: 6.4871x; 1.0377x over previous
//
#include <hip/hip_runtime.h>
#include <hip/hip_fp16.h>

#define NF 14
#define DIMOUT 16
#define BSH 9        // 512 nodes per bucket
#define NPBKT 512
#define NBKT 256     // bucket count (used: ceil(N/512) = 196)
#define C1 4096      // edges per block in bucket passes
#define HNODES 256   // nodes per half-bucket
#define SCAP 14336   // LDS staging capacity (entries) per half-bucket

// int64 edge buffer <=> odd 32-bit words (high halves) all zero (ids < 2^31)
__device__ __forceinline__ bool detect64(const int* e32) {
    bool is64 = true;
#pragma unroll
    for (int i = 1; i < 64; i += 2) is64 &= (e32[i] == 0);
    return is64;
}

// ---- per-block bucket histogram (transposed write); 16B paired loads ----
__global__ __launch_bounds__(256) void k_lhist(const void* __restrict__ edges,
                                               int* __restrict__ lhistT, int E, int NBLK) {
    __shared__ int h[NBKT];
    const int t = threadIdx.x;
    h[t] = 0;
    __syncthreads();
    const int* e32 = (const int*)edges;
    const long long* e64 = (const long long*)edges;
    const bool is64 = detect64(e32);
    const int base = blockIdx.x * C1;
    const int cnt = min(C1, E - base);  // always even (E, C1 even)
    if (is64) {
        const longlong2* p2 = (const longlong2*)(e64 + (size_t)E + base);
        for (int j = 2 * t; j < cnt; j += 512) {
            longlong2 v = p2[j >> 1];
            atomicAdd(&h[((int)v.x) >> BSH], 1);
            atomicAdd(&h[((int)v.y) >> BSH], 1);
        }
    } else {
        const int2* p2 = (const int2*)(e32 + (size_t)E + base);
        for (int j = 2 * t; j < cnt; j += 512) {
            int2 v = p2[j >> 1];
            atomicAdd(&h[v.x >> BSH], 1);
            atomicAdd(&h[v.y >> BSH], 1);
        }
    }
    __syncthreads();
    lhistT[(size_t)t * NBLK + blockIdx.x] = h[t];
}

// ---- per-bucket scan over blocks ----
__global__ __launch_bounds__(256) void k_cscan(const int* __restrict__ lhistT,
                                               int* __restrict__ lbase,
                                               int* __restrict__ btot, int NBLK) {
    const int b = blockIdx.x;
    const int t = threadIdx.x;
    const int IPT = (NBLK + 255) / 256;
    int v[8];
    int s = 0;
    for (int k = 0; k < IPT; ++k) {
        int j = t * IPT + k;
        int x = (j < NBLK) ? lhistT[(size_t)b * NBLK + j] : 0;
        v[k] = x;
        s += x;
    }
    __shared__ int sm[256];
    sm[t] = s;
    __syncthreads();
    for (int d = 1; d < 256; d <<= 1) {
        int u = (t >= d) ? sm[t - d] : 0;
        __syncthreads();
        sm[t] += u;
        __syncthreads();
    }
    int run = sm[t] - s;
    for (int k = 0; k < IPT; ++k) {
        int j = t * IPT + k;
        if (j < NBLK) {
            lbase[(size_t)b * NBLK + j] = run;
            run += v[k];
        }
    }
    if (t == 255) btot[b] = sm[255];
}

// ---- scan bucket totals -> regions; also zero the hbuild cursor ----
__global__ __launch_bounds__(NBKT) void k_gscan(const int* __restrict__ btot,
                                                int* __restrict__ gregion,
                                                int* __restrict__ cursor) {
    __shared__ int sm[NBKT];
    int t = threadIdx.x;
    int v = btot[t];
    sm[t] = v;
    __syncthreads();
    for (int d = 1; d < NBKT; d <<= 1) {
        int u = (t >= d) ? sm[t - d] : 0;
        __syncthreads();
        sm[t] += u;
        __syncthreads();
    }
    gregion[t] = sm[t] - v;
    if (t == NBKT - 1) gregion[NBKT] = sm[t];
    if (t == 0) cursor[0] = 0;
}

// ---- bucket scatter: block-local LDS counting sort, runs at exact bases ----
// packed entry: (dst & 511) << 17 | src ; 16B paired edge loads
__global__ __launch_bounds__(256) void k_scatter(const void* __restrict__ edges,
                                                 const int* __restrict__ gregion,
                                                 const int* __restrict__ lbase,
                                                 unsigned int* __restrict__ pairs,
                                                 int E, int NBLK) {
    __shared__ unsigned int raw[C1];
    __shared__ unsigned int srt[C1];
    __shared__ unsigned short bkt[C1];
    __shared__ unsigned char sbk[C1];
    __shared__ int hist[NBKT], scn[NBKT], gb[NBKT], cur[NBKT];
    const int* e32 = (const int*)edges;
    const long long* e64 = (const long long*)edges;
    const bool is64 = detect64(e32);
    const int t = threadIdx.x;
    const int base = blockIdx.x * C1;
    const int cnt = min(C1, E - base);  // always even
    hist[t] = 0;
    cur[t] = 0;
    __syncthreads();
    for (int j = 2 * t; j < cnt; j += 512) {
        int s0, s1, d0, d1;
        if (is64) {
            longlong2 vs = *(const longlong2*)(e64 + (size_t)base + j);
            longlong2 vd = *(const longlong2*)(e64 + (size_t)E + base + j);
            s0 = (int)vs.x;
            s1 = (int)vs.y;
            d0 = (int)vd.x;
            d1 = (int)vd.y;
        } else {
            int2 vs = *(const int2*)(e32 + (size_t)base + j);
            int2 vd = *(const int2*)(e32 + (size_t)E + base + j);
            s0 = vs.x;
            s1 = vs.y;
            d0 = vd.x;
            d1 = vd.y;
        }
        int b0 = d0 >> BSH, b1 = d1 >> BSH;
        raw[j] = (unsigned int)s0 | ((unsigned int)(d0 & (NPBKT - 1)) << 17);
        raw[j + 1] = (unsigned int)s1 | ((unsigned int)(d1 & (NPBKT - 1)) << 17);
        bkt[j] = (unsigned short)b0;
        bkt[j + 1] = (unsigned short)b1;
        atomicAdd(&hist[b0], 1);
        atomicAdd(&hist[b1], 1);
    }
    __syncthreads();
    int v = hist[t];
    scn[t] = v;
    __syncthreads();
    for (int d = 1; d < NBKT; d <<= 1) {
        int u = (t >= d) ? scn[t - d] : 0;
        __syncthreads();
        scn[t] += u;
        __syncthreads();
    }
    int ex = scn[t] - v;
    gb[t] = gregion[t] + lbase[(size_t)t * NBLK + blockIdx.x];
    __syncthreads();
    scn[t] = ex;
    __syncthreads();
    for (int j = t; j < cnt; j += 256) {
        int b = bkt[j];
        int r = atomicAdd(&cur[b], 1);
        int pos = scn[b] + r;
        srt[pos] = raw[j];
        sbk[pos] = (unsigned char)b;
    }
    __syncthreads();
    for (int j = t; j < cnt; j += 256) {
        int b = sbk[j];
        pairs[gb[b] + (j - scn[b])] = srt[j];
    }
}

// ---- fused half-bucket build: count -> reserve segment -> stage -> burst ----
// One block per half-bucket (256 nodes). Counts degrees in LDS, reserves its
// srcs segment via one global atomicAdd (content per node is deterministic;
// only segment placement varies, and off2 always matches), writes dinv/off2,
// stages self-loop + edges + sentinel pads in LDS, burst-writes coalesced.
__global__ __launch_bounds__(512) void k_hbuild(const unsigned int* __restrict__ pairs,
                                                const int* __restrict__ gregion,
                                                int* __restrict__ cursor,
                                                float* __restrict__ dinv,
                                                int2* __restrict__ off2,
                                                int* __restrict__ srcs, int N) {
    const int bh = blockIdx.x;
    const int b = bh >> 1, h = bh & 1;
    const int e0 = gregion[b], e1 = gregion[b + 1];
    __shared__ int cnt[HNODES], sm[HNODES], cur[HNODES];
    __shared__ unsigned staged[SCAP];
    __shared__ int gb_sh;
    const int t = threadIdx.x;
    if (t < HNODES) cnt[t] = 0;
    __syncthreads();
    for (int e = e0 + t; e < e1; e += 512) {
        int dl = (int)(pairs[e] >> 17);
        if ((dl >> 8) == h) atomicAdd(&cnt[dl & (HNODES - 1)], 1);
    }
    __syncthreads();
    const int nbase = (b << BSH) + h * HNODES;
    int c = 0, p = 0;
    if (t < HNODES) {
        c = cnt[t];
        if (nbase + t < N) p = (c + 8) & ~7;  // self-loop + pad to 8
        sm[t] = p;
    }
    __syncthreads();
    for (int d = 1; d < HNODES; d <<= 1) {
        int u = (t >= d && t < HNODES) ? sm[t - d] : 0;
        __syncthreads();
        if (t < HNODES) sm[t] += u;
        __syncthreads();
    }
    const int span = sm[HNODES - 1];
    if (t == 0) gb_sh = atomicAdd(cursor, span);
    __syncthreads();
    const int gb = gb_sh;
    const bool fits = (span <= SCAP);
    if (t < HNODES) {
        int n = nbase + t;
        if (n < N) {
            int loff = sm[t] - p;
            dinv[n] = rsqrtf((float)(c + 1));
            off2[n] = make_int2(gb + loff, gb + loff + p);
            if (fits) {
                cur[t] = loff + 1;
                staged[loff] = (unsigned)n;  // self loop at slot 0
                for (int k = c + 1; k < p; ++k) staged[loff + k] = (unsigned)N;
            } else {  // fallback: direct global writes
                cur[t] = gb + loff + 1;
                srcs[gb + loff] = n;
                for (int k = c + 1; k < p; ++k) srcs[gb + loff + k] = N;
            }
        } else {
            cur[t] = 0;
        }
    }
    __syncthreads();
    if (fits) {
        for (int e = e0 + t; e < e1; e += 512) {  // L2-hot re-read
            unsigned pr = pairs[e];
            int dl = (int)(pr >> 17);
            if ((dl >> 8) == h) {
                int r = atomicAdd(&cur[dl & (HNODES - 1)], 1);  // LDS only
                staged[r] = pr & 0x1FFFFu;
            }
        }
        __syncthreads();
        for (int i = t; i < span; i += 512) srcs[gb + i] = (int)staged[i];
    } else {
        for (int e = e0 + t; e < e1; e += 512) {
            unsigned pr = pairs[e];
            int dl = (int)(pr >> 17);
            if ((dl >> 8) == h) {
                int r = atomicAdd(&cur[dl & (HNODES - 1)], 1);
                srcs[r] = (int)(pr & 0x1FFFFu);
            }
        }
    }
}

// ---- prep: u0[n] = fp16( dinv[n] * (x[n] @ W^T) ); zero sentinel rows ----
__global__ __launch_bounds__(256) void k_prep(const float* __restrict__ x,
                                              const float* __restrict__ dinv,
                                              const float* __restrict__ Wg,
                                              __half2* __restrict__ u0,
                                              __half2* __restrict__ u1, int N) {
    __shared__ float Wl[DIMOUT * NF];
    int t = threadIdx.x;
    if (t < DIMOUT * NF) Wl[t] = Wg[t];
    __syncthreads();
    if (blockIdx.x == 0 && t < 8) {  // zero sentinel rows (src == N)
        u0[(size_t)N * 8 + t] = __floats2half2_rn(0.f, 0.f);
        u1[(size_t)N * 8 + t] = __floats2half2_rn(0.f, 0.f);
    }
    int n = blockIdx.x * 256 + t;
    if (n >= N) return;
    float xr[NF];
    const float2* xr2 = (const float2*)(x + (size_t)n * NF);
#pragma unroll
    for (int k = 0; k < 7; ++k) {
        float2 v = xr2[k];
        xr[2 * k] = v.x;
        xr[2 * k + 1] = v.y;
    }
    float dn = dinv[n];
#pragma unroll
    for (int q = 0; q < 8; ++q) {
        float r0 = 0.f, r1 = 0.f;
#pragma unroll
        for (int f = 0; f < NF; ++f) {
            r0 += xr[f] * Wl[(2 * q) * NF + f];
            r1 += xr[f] * Wl[(2 * q + 1) * NF + f];
        }
        u0[(size_t)n * 8 + q] = __floats2half2_rn(dn * r0, dn * r1);
    }
}

// ---- hop: grid-stride, 2 nodes per wave (half-wave each), 8-way
// edge-parallel, 8B lanes, pad-8 lists. Reduce over ep = 3 shfl rounds. ----
template <int FINAL>
__global__ __launch_bounds__(256) void k_hop(const uint2* __restrict__ u8,
                                             const int* __restrict__ srcs,
                                             const int2* __restrict__ off2,
                                             const float* __restrict__ dinv,
                                             const float* __restrict__ bias,
                                             uint2* __restrict__ outh,
                                             float* __restrict__ outf, int N) {
    const int lane = threadIdx.x & 63;
    const int fp = lane & 3;          // 8B quarter of 32B row
    const int ep = (lane >> 2) & 7;   // 8 edge subgroups per half-wave
    const int half = lane >> 5;       // which node this half-wave owns
    const int wid = threadIdx.x >> 6;
    float4 breg = make_float4(0.f, 0.f, 0.f, 0.f);
    if (FINAL) breg = *(const float4*)(bias + 4 * fp);
    const int stride = gridDim.x * 8;  // 4 waves x 2 nodes per block
    for (int n0 = blockIdx.x * 8 + wid * 2; n0 < N; n0 += stride) {
        const int n = n0 + half;
        const bool act = (n < N);
        int2 oo = act ? off2[n] : make_int2(0, 0);
        float ax = 0.f, ay = 0.f, az = 0.f, aw = 0.f;
        int e = oo.x + ep;
        for (; e + 8 < oo.y; e += 16) {  // 2-deep: 16 slots per half-wave iter
            int s0 = srcs[e];
            int s1 = srcs[e + 8];
            uint2 q0 = u8[(size_t)s0 * 4 + fp];
            uint2 q1 = u8[(size_t)s1 * 4 + fp];
            float2 a0 = __half22float2(*(__half2*)&q0.x);
            float2 b0 = __half22float2(*(__half2*)&q0.y);
            float2 a1 = __half22float2(*(__half2*)&q1.x);
            float2 b1 = __half22float2(*(__half2*)&q1.y);
            ax += a0.x + a1.x;
            ay += a0.y + a1.y;
            az += b0.x + b1.x;
            aw += b0.y + b1.y;
        }
        if (e < oo.y) {  // at most one leftover 8-chunk
            int s0 = srcs[e];
            uint2 q0 = u8[(size_t)s0 * 4 + fp];
            float2 a0 = __half22float2(*(__half2*)&q0.x);
            float2 b0 = __half22float2(*(__half2*)&q0.y);
            ax += a0.x;
            ay += a0.y;
            az += b0.x;
            aw += b0.y;
        }
#pragma unroll
        for (int d = 4; d <= 16; d <<= 1) {  // reduce over ep, stays in-half
            ax += __shfl_xor(ax, d);
            ay += __shfl_xor(ay, d);
            az += __shfl_xor(az, d);
            aw += __shfl_xor(aw, d);
        }
        if (ep == 0 && act) {
            float dn = dinv[n];
            if (!FINAL) {
                float s = dn * dn;
                __half2 h0 = __floats2half2_rn(s * ax, s * ay);
                __half2 h1 = __floats2half2_rn(s * az, s * aw);
                uint2 q;
                q.x = *(unsigned*)&h0;
                q.y = *(unsigned*)&h1;
                outh[(size_t)n * 4 + fp] = q;
            } else {
                float4 o;
                o.x = dn * ax + breg.x;
                o.y = dn * ay + breg.y;
                o.z = dn * az + breg.z;
                o.w = dn * aw + breg.w;
                *(float4*)(outf + (size_t)n * DIMOUT + 4 * fp) = o;
            }
        }
    }
}

extern "C" void kernel_launch(void* const* d_in, const int* in_sizes, int n_in,
                              void* d_out, int out_size, void* d_ws, size_t ws_size,
                              hipStream_t stream) {
    const float* x = (const float*)d_in[0];
    const void* edges = d_in[1];
    const float* W = (const float*)d_in[2];
    const float* b = (const float*)d_in[3];
    float* out = (float*)d_out;

    const int N = in_sizes[0] / NF;  // 100000
    const int E = in_sizes[1] / 2;   // 3200000
    const int NBLK = (E + C1 - 1) / C1;
    const int NUSED = (N + NPBKT - 1) >> BSH;
    const int NBH = NUSED * 2;  // half-buckets

    char* ws = (char*)d_ws;
    size_t o = 0;
    auto alloc = [&](size_t bytes) -> void* {
        o = (o + 255) & ~(size_t)255;
        void* p = ws + o;
        o += bytes;
        return p;
    };
    int* cursor = (int*)alloc(16);
    int* lhistT = (int*)alloc((size_t)NBKT * NBLK * sizeof(int));
    int* lbase = (int*)alloc((size_t)NBKT * NBLK * sizeof(int));
    int* btot = (int*)alloc((size_t)NBKT * sizeof(int));
    int* gregion = (int*)alloc(((size_t)NBKT + 1) * sizeof(int));
    unsigned int* pairs = (unsigned int*)alloc((size_t)E * sizeof(unsigned int));
    int* srcs = (int*)alloc(((size_t)E + (size_t)8 * N + 256) * sizeof(int));
    int2* off2 = (int2*)alloc((size_t)N * sizeof(int2));
    float* dinv = (float*)alloc((size_t)N * sizeof(float));
    __half* u0 = (__half*)alloc((size_t)(N + 1) * 16 * sizeof(__half));
    __half* u1 = (__half*)alloc((size_t)(N + 1) * 16 * sizeof(__half));
    (void)ws_size;
    (void)n_in;
    (void)out_size;

    k_lhist<<<NBLK, 256, 0, stream>>>(edges, lhistT, E, NBLK);
    k_cscan<<<NBKT, 256, 0, stream>>>(lhistT, lbase, btot, NBLK);
    k_gscan<<<1, NBKT, 0, stream>>>(btot, gregion, cursor);
    k_scatter<<<NBLK, 256, 0, stream>>>(edges, gregion, lbase, pairs, E, NBLK);
    k_hbuild<<<NBH, 512, 0, stream>>>(pairs, gregion, cursor, dinv, off2, srcs, N);
    k_prep<<<(N + 255) / 256, 256, 0, stream>>>(x, dinv, W, (__half2*)u0,
                                                (__half2*)u1, N);

    k_hop<0><<<2048, 256, 0, stream>>>((const uint2*)u0, srcs, off2, dinv, nullptr,
                                       (uint2*)u1, nullptr, N);
    k_hop<1><<<2048, 256, 0, stream>>>((const uint2*)u1, srcs, off2, dinv, b,
                                       nullptr, out, N);
}

// Round 18
// 113.460 us; speedup vs baseline: 6.6857x; 1.0306x over previous
//
#include <hip/hip_runtime.h>
#include <hip/hip_fp16.h>

#define NF 14
#define DIMOUT 16
#define BSH 9        // 512 nodes per bucket
#define NPBKT 512
#define NBKT 256     // bucket count (used: ceil(N/512) = 196)
#define C1 4096      // edges per block in bucket passes
#define HNODES 256   // nodes per half-bucket
#define SCAP 14336   // LDS staging capacity (entries) per half-bucket

// int64 edge buffer <=> odd 32-bit words (high halves) all zero (ids < 2^31)
__device__ __forceinline__ bool detect64(const int* e32) {
    bool is64 = true;
#pragma unroll
    for (int i = 1; i < 64; i += 2) is64 &= (e32[i] == 0);
    return is64;
}

// ---- per-block bucket histogram (transposed write); 16B paired loads ----
__global__ __launch_bounds__(256) void k_lhist(const void* __restrict__ edges,
                                               int* __restrict__ lhistT, int E, int NBLK) {
    __shared__ int h[NBKT];
    const int t = threadIdx.x;
    h[t] = 0;
    __syncthreads();
    const int* e32 = (const int*)edges;
    const long long* e64 = (const long long*)edges;
    const bool is64 = detect64(e32);
    const int base = blockIdx.x * C1;
    const int cnt = min(C1, E - base);  // always even (E, C1 even)
    if (is64) {
        const longlong2* p2 = (const longlong2*)(e64 + (size_t)E + base);
        for (int j = 2 * t; j < cnt; j += 512) {
            longlong2 v = p2[j >> 1];
            atomicAdd(&h[((int)v.x) >> BSH], 1);
            atomicAdd(&h[((int)v.y) >> BSH], 1);
        }
    } else {
        const int2* p2 = (const int2*)(e32 + (size_t)E + base);
        for (int j = 2 * t; j < cnt; j += 512) {
            int2 v = p2[j >> 1];
            atomicAdd(&h[v.x >> BSH], 1);
            atomicAdd(&h[v.y >> BSH], 1);
        }
    }
    __syncthreads();
    lhistT[(size_t)t * NBLK + blockIdx.x] = h[t];
}

// ---- per-bucket scan over blocks ----
__global__ __launch_bounds__(256) void k_cscan(const int* __restrict__ lhistT,
                                               int* __restrict__ lbase,
                                               int* __restrict__ btot, int NBLK) {
    const int b = blockIdx.x;
    const int t = threadIdx.x;
    const int IPT = (NBLK + 255) / 256;
    int v[8];
    int s = 0;
    for (int k = 0; k < IPT; ++k) {
        int j = t * IPT + k;
        int x = (j < NBLK) ? lhistT[(size_t)b * NBLK + j] : 0;
        v[k] = x;
        s += x;
    }
    __shared__ int sm[256];
    sm[t] = s;
    __syncthreads();
    for (int d = 1; d < 256; d <<= 1) {
        int u = (t >= d) ? sm[t - d] : 0;
        __syncthreads();
        sm[t] += u;
        __syncthreads();
    }
    int run = sm[t] - s;
    for (int k = 0; k < IPT; ++k) {
        int j = t * IPT + k;
        if (j < NBLK) {
            lbase[(size_t)b * NBLK + j] = run;
            run += v[k];
        }
    }
    if (t == 255) btot[b] = sm[255];
}

// ---- scan bucket totals -> regions; zero hbuild cursor + sentinel rows ----
__global__ __launch_bounds__(NBKT) void k_gscan(const int* __restrict__ btot,
                                                int* __restrict__ gregion,
                                                int* __restrict__ cursor,
                                                __half2* __restrict__ u0,
                                                __half2* __restrict__ u1, int N) {
    __shared__ int sm[NBKT];
    int t = threadIdx.x;
    int v = btot[t];
    sm[t] = v;
    __syncthreads();
    for (int d = 1; d < NBKT; d <<= 1) {
        int u = (t >= d) ? sm[t - d] : 0;
        __syncthreads();
        sm[t] += u;
        __syncthreads();
    }
    gregion[t] = sm[t] - v;
    if (t == NBKT - 1) gregion[NBKT] = sm[t];
    if (t == 0) cursor[0] = 0;
    if (t < 8) {  // zero sentinel rows (src == N)
        u0[(size_t)N * 8 + t] = __floats2half2_rn(0.f, 0.f);
        u1[(size_t)N * 8 + t] = __floats2half2_rn(0.f, 0.f);
    }
}

// ---- bucket scatter: block-local LDS counting sort, runs at exact bases ----
// packed entry: (dst & 511) << 17 | src ; 16B paired edge loads
__global__ __launch_bounds__(256) void k_scatter(const void* __restrict__ edges,
                                                 const int* __restrict__ gregion,
                                                 const int* __restrict__ lbase,
                                                 unsigned int* __restrict__ pairs,
                                                 int E, int NBLK) {
    __shared__ unsigned int raw[C1];
    __shared__ unsigned int srt[C1];
    __shared__ unsigned short bkt[C1];
    __shared__ unsigned char sbk[C1];
    __shared__ int hist[NBKT], scn[NBKT], gb[NBKT], cur[NBKT];
    const int* e32 = (const int*)edges;
    const long long* e64 = (const long long*)edges;
    const bool is64 = detect64(e32);
    const int t = threadIdx.x;
    const int base = blockIdx.x * C1;
    const int cnt = min(C1, E - base);  // always even
    hist[t] = 0;
    cur[t] = 0;
    __syncthreads();
    for (int j = 2 * t; j < cnt; j += 512) {
        int s0, s1, d0, d1;
        if (is64) {
            longlong2 vs = *(const longlong2*)(e64 + (size_t)base + j);
            longlong2 vd = *(const longlong2*)(e64 + (size_t)E + base + j);
            s0 = (int)vs.x;
            s1 = (int)vs.y;
            d0 = (int)vd.x;
            d1 = (int)vd.y;
        } else {
            int2 vs = *(const int2*)(e32 + (size_t)base + j);
            int2 vd = *(const int2*)(e32 + (size_t)E + base + j);
            s0 = vs.x;
            s1 = vs.y;
            d0 = vd.x;
            d1 = vd.y;
        }
        int b0 = d0 >> BSH, b1 = d1 >> BSH;
        raw[j] = (unsigned int)s0 | ((unsigned int)(d0 & (NPBKT - 1)) << 17);
        raw[j + 1] = (unsigned int)s1 | ((unsigned int)(d1 & (NPBKT - 1)) << 17);
        bkt[j] = (unsigned short)b0;
        bkt[j + 1] = (unsigned short)b1;
        atomicAdd(&hist[b0], 1);
        atomicAdd(&hist[b1], 1);
    }
    __syncthreads();
    int v = hist[t];
    scn[t] = v;
    __syncthreads();
    for (int d = 1; d < NBKT; d <<= 1) {
        int u = (t >= d) ? scn[t - d] : 0;
        __syncthreads();
        scn[t] += u;
        __syncthreads();
    }
    int ex = scn[t] - v;
    gb[t] = gregion[t] + lbase[(size_t)t * NBLK + blockIdx.x];
    __syncthreads();
    scn[t] = ex;
    __syncthreads();
    for (int j = t; j < cnt; j += 256) {
        int b = bkt[j];
        int r = atomicAdd(&cur[b], 1);
        int pos = scn[b] + r;
        srt[pos] = raw[j];
        sbk[pos] = (unsigned char)b;
    }
    __syncthreads();
    for (int j = t; j < cnt; j += 256) {
        int b = sbk[j];
        pairs[gb[b] + (j - scn[b])] = srt[j];
    }
}

// ---- fused half-bucket build: count -> reserve -> stage -> burst -> prep ----
// One block per half-bucket (256 nodes). Counts degrees in LDS, reserves its
// srcs segment via one global atomicAdd, writes dinv/off2, stages self-loop +
// edges + sentinel pads in LDS, burst-writes coalesced, then computes
// u0[n] = fp16(dinv * (x[n] @ W^T)) for its nodes (2 threads/node).
__global__ __launch_bounds__(512) void k_hbuild(const unsigned int* __restrict__ pairs,
                                                const int* __restrict__ gregion,
                                                int* __restrict__ cursor,
                                                const float* __restrict__ x,
                                                const float* __restrict__ Wg,
                                                float* __restrict__ dinv,
                                                int2* __restrict__ off2,
                                                int* __restrict__ srcs,
                                                __half2* __restrict__ u0, int N) {
    const int bh = blockIdx.x;
    const int b = bh >> 1, h = bh & 1;
    const int e0 = gregion[b], e1 = gregion[b + 1];
    __shared__ int cnt[HNODES], sm[HNODES], cur[HNODES];
    __shared__ float Wl[DIMOUT * NF];
    __shared__ unsigned staged[SCAP];
    __shared__ int gb_sh;
    const int t = threadIdx.x;
    if (t < HNODES) cnt[t] = 0;
    if (t >= HNODES && t - HNODES < DIMOUT * NF) Wl[t - HNODES] = Wg[t - HNODES];
    __syncthreads();
    for (int e = e0 + t; e < e1; e += 512) {
        int dl = (int)(pairs[e] >> 17);
        if ((dl >> 8) == h) atomicAdd(&cnt[dl & (HNODES - 1)], 1);
    }
    __syncthreads();
    const int nbase = (b << BSH) + h * HNODES;
    int c = 0, p = 0;
    if (t < HNODES) {
        c = cnt[t];
        if (nbase + t < N) p = (c + 8) & ~7;  // self-loop + pad to 8
        sm[t] = p;
    }
    __syncthreads();
    for (int d = 1; d < HNODES; d <<= 1) {
        int u = (t >= d && t < HNODES) ? sm[t - d] : 0;
        __syncthreads();
        if (t < HNODES) sm[t] += u;
        __syncthreads();
    }
    const int span = sm[HNODES - 1];
    if (t == 0) gb_sh = atomicAdd(cursor, span);
    __syncthreads();
    const int gb = gb_sh;
    const bool fits = (span <= SCAP);
    if (t < HNODES) {
        int n = nbase + t;
        if (n < N) {
            int loff = sm[t] - p;
            dinv[n] = rsqrtf((float)(c + 1));
            off2[n] = make_int2(gb + loff, gb + loff + p);
            if (fits) {
                cur[t] = loff + 1;
                staged[loff] = (unsigned)n;  // self loop at slot 0
                for (int k = c + 1; k < p; ++k) staged[loff + k] = (unsigned)N;
            } else {  // fallback: direct global writes
                cur[t] = gb + loff + 1;
                srcs[gb + loff] = n;
                for (int k = c + 1; k < p; ++k) srcs[gb + loff + k] = N;
            }
        } else {
            cur[t] = 0;
        }
    }
    __syncthreads();
    if (fits) {
        for (int e = e0 + t; e < e1; e += 512) {  // L2-hot re-read
            unsigned pr = pairs[e];
            int dl = (int)(pr >> 17);
            if ((dl >> 8) == h) {
                int r = atomicAdd(&cur[dl & (HNODES - 1)], 1);  // LDS only
                staged[r] = pr & 0x1FFFFu;
            }
        }
        __syncthreads();
        for (int i = t; i < span; i += 512) srcs[gb + i] = (int)staged[i];
    } else {
        for (int e = e0 + t; e < e1; e += 512) {
            unsigned pr = pairs[e];
            int dl = (int)(pr >> 17);
            if ((dl >> 8) == h) {
                int r = atomicAdd(&cur[dl & (HNODES - 1)], 1);
                srcs[r] = (int)(pr & 0x1FFFFu);
            }
        }
    }
    // ---- prep tail: 2 threads per node, 4 half2 outputs each.
    // Reads only cnt[] (stable since count phase) + global x/W — no sync needed.
    const int l2 = t >> 1;
    const int n2 = nbase + l2;
    if (n2 < N) {
        const int qb = (t & 1) * 4;
        float dn = rsqrtf((float)(cnt[l2] + 1));
        float xr[NF];
        const float2* xr2 = (const float2*)(x + (size_t)n2 * NF);
#pragma unroll
        for (int k = 0; k < 7; ++k) {
            float2 v = xr2[k];
            xr[2 * k] = v.x;
            xr[2 * k + 1] = v.y;
        }
#pragma unroll
        for (int q = 0; q < 4; ++q) {
            const int qq = qb + q;
            float r0 = 0.f, r1 = 0.f;
#pragma unroll
            for (int f = 0; f < NF; ++f) {
                r0 += xr[f] * Wl[(2 * qq) * NF + f];
                r1 += xr[f] * Wl[(2 * qq + 1) * NF + f];
            }
            u0[(size_t)n2 * 8 + qq] = __floats2half2_rn(dn * r0, dn * r1);
        }
    }
}

// ---- hop: grid-stride, 2 nodes per wave (half-wave each), 8-way
// edge-parallel, 8B lanes, pad-8 lists. Reduce over ep = 3 shfl rounds. ----
template <int FINAL>
__global__ __launch_bounds__(256) void k_hop(const uint2* __restrict__ u8,
                                             const int* __restrict__ srcs,
                                             const int2* __restrict__ off2,
                                             const float* __restrict__ dinv,
                                             const float* __restrict__ bias,
                                             uint2* __restrict__ outh,
                                             float* __restrict__ outf, int N) {
    const int lane = threadIdx.x & 63;
    const int fp = lane & 3;          // 8B quarter of 32B row
    const int ep = (lane >> 2) & 7;   // 8 edge subgroups per half-wave
    const int half = lane >> 5;       // which node this half-wave owns
    const int wid = threadIdx.x >> 6;
    float4 breg = make_float4(0.f, 0.f, 0.f, 0.f);
    if (FINAL) breg = *(const float4*)(bias + 4 * fp);
    const int stride = gridDim.x * 8;  // 4 waves x 2 nodes per block
    for (int n0 = blockIdx.x * 8 + wid * 2; n0 < N; n0 += stride) {
        const int n = n0 + half;
        const bool act = (n < N);
        int2 oo = act ? off2[n] : make_int2(0, 0);
        float ax = 0.f, ay = 0.f, az = 0.f, aw = 0.f;
        int e = oo.x + ep;
        for (; e + 8 < oo.y; e += 16) {  // 2-deep: 16 slots per half-wave iter
            int s0 = srcs[e];
            int s1 = srcs[e + 8];
            uint2 q0 = u8[(size_t)s0 * 4 + fp];
            uint2 q1 = u8[(size_t)s1 * 4 + fp];
            float2 a0 = __half22float2(*(__half2*)&q0.x);
            float2 b0 = __half22float2(*(__half2*)&q0.y);
            float2 a1 = __half22float2(*(__half2*)&q1.x);
            float2 b1 = __half22float2(*(__half2*)&q1.y);
            ax += a0.x + a1.x;
            ay += a0.y + a1.y;
            az += b0.x + b1.x;
            aw += b0.y + b1.y;
        }
        if (e < oo.y) {  // at most one leftover 8-chunk
            int s0 = srcs[e];
            uint2 q0 = u8[(size_t)s0 * 4 + fp];
            float2 a0 = __half22float2(*(__half2*)&q0.x);
            float2 b0 = __half22float2(*(__half2*)&q0.y);
            ax += a0.x;
            ay += a0.y;
            az += b0.x;
            aw += b0.y;
        }
#pragma unroll
        for (int d = 4; d <= 16; d <<= 1) {  // reduce over ep, stays in-half
            ax += __shfl_xor(ax, d);
            ay += __shfl_xor(ay, d);
            az += __shfl_xor(az, d);
            aw += __shfl_xor(aw, d);
        }
        if (ep == 0 && act) {
            float dn = dinv[n];
            if (!FINAL) {
                float s = dn * dn;
                __half2 h0 = __floats2half2_rn(s * ax, s * ay);
                __half2 h1 = __floats2half2_rn(s * az, s * aw);
                uint2 q;
                q.x = *(unsigned*)&h0;
                q.y = *(unsigned*)&h1;
                outh[(size_t)n * 4 + fp] = q;
            } else {
                float4 o;
                o.x = dn * ax + breg.x;
                o.y = dn * ay + breg.y;
                o.z = dn * az + breg.z;
                o.w = dn * aw + breg.w;
                *(float4*)(outf + (size_t)n * DIMOUT + 4 * fp) = o;
            }
        }
    }
}

extern "C" void kernel_launch(void* const* d_in, const int* in_sizes, int n_in,
                              void* d_out, int out_size, void* d_ws, size_t ws_size,
                              hipStream_t stream) {
    const float* x = (const float*)d_in[0];
    const void* edges = d_in[1];
    const float* W = (const float*)d_in[2];
    const float* b = (const float*)d_in[3];
    float* out = (float*)d_out;

    const int N = in_sizes[0] / NF;  // 100000
    const int E = in_sizes[1] / 2;   // 3200000
    const int NBLK = (E + C1 - 1) / C1;
    const int NUSED = (N + NPBKT - 1) >> BSH;
    const int NBH = NUSED * 2;  // half-buckets

    char* ws = (char*)d_ws;
    size_t o = 0;
    auto alloc = [&](size_t bytes) -> void* {
        o = (o + 255) & ~(size_t)255;
        void* p = ws + o;
        o += bytes;
        return p;
    };
    int* cursor = (int*)alloc(16);
    int* lhistT = (int*)alloc((size_t)NBKT * NBLK * sizeof(int));
    int* lbase = (int*)alloc((size_t)NBKT * NBLK * sizeof(int));
    int* btot = (int*)alloc((size_t)NBKT * sizeof(int));
    int* gregion = (int*)alloc(((size_t)NBKT + 1) * sizeof(int));
    unsigned int* pairs = (unsigned int*)alloc((size_t)E * sizeof(unsigned int));
    int* srcs = (int*)alloc(((size_t)E + (size_t)8 * N + 256) * sizeof(int));
    int2* off2 = (int2*)alloc((size_t)N * sizeof(int2));
    float* dinv = (float*)alloc((size_t)N * sizeof(float));
    __half* u0 = (__half*)alloc((size_t)(N + 1) * 16 * sizeof(__half));
    __half* u1 = (__half*)alloc((size_t)(N + 1) * 16 * sizeof(__half));
    (void)ws_size;
    (void)n_in;
    (void)out_size;

    k_lhist<<<NBLK, 256, 0, stream>>>(edges, lhistT, E, NBLK);
    k_cscan<<<NBKT, 256, 0, stream>>>(lhistT, lbase, btot, NBLK);
    k_gscan<<<1, NBKT, 0, stream>>>(btot, gregion, cursor, (__half2*)u0,
                                    (__half2*)u1, N);
    k_scatter<<<NBLK, 256, 0, stream>>>(edges, gregion, lbase, pairs, E, NBLK);
    k_hbuild<<<NBH, 512, 0, stream>>>(pairs, gregion, cursor, x, W, dinv, off2,
                                      srcs, (__half2*)u0, N);

    k_hop<0><<<2048, 256, 0, stream>>>((const uint2*)u0, srcs, off2, dinv, nullptr,
                                       (uint2*)u1, nullptr, N);
    k_hop<1><<<2048, 256, 0, stream>>>((const uint2*)u1, srcs, off2, dinv, b,
                                       nullptr, out, N);
}